// Round 1
// baseline (1758.544 us; speedup 1.0000x reference)
//
#include <hip/hip_runtime.h>
#include <hip/hip_bf16.h>
#include <math.h>

#define N_NODES 50000
#define N_EDGES 600000
#define DIM 128
#define N_REL 8
#define N_BASES 8
#define N_GRAPHS 256
#define NB 16                 // nodes per block in layer kernel (50000 = 3125*16 exact)
#define KDIM (N_BASES * DIM)  // 1024

static __device__ __forceinline__ int lower_bound_i(const int* a, int n, int v) {
    int lo = 0, hi = n;
    while (lo < hi) { int mid = (lo + hi) >> 1; if (a[mid] < v) lo = mid + 1; else hi = mid; }
    return lo;
}

__global__ void k_zero_i(int* p, int n) {
    int i = blockIdx.x * blockDim.x + threadIdx.x;
    if (i < n) p[i] = 0;
}

__global__ void k_count(const int* __restrict__ dst, int* __restrict__ counts, int e) {
    int i = blockIdx.x * blockDim.x + threadIdx.x;
    if (i < e) atomicAdd(&counts[dst[i]], 1);
}

// cnt_cursor: in = per-node counts, out = running cursor (= exclusive offsets).
// offsets: exclusive prefix sum, offsets[n] = total.
__global__ __launch_bounds__(1024) void k_scan(int* cnt_cursor, int* __restrict__ offsets, int n) {
    const int tid = threadIdx.x;
    const int C = (n + 1023) >> 10;  // 49 for n=50000
    __shared__ int ssc[1024];
    const int base = tid * C;
    int mysum = 0;
    for (int j = 0; j < C; j++) { int idx = base + j; if (idx < n) mysum += cnt_cursor[idx]; }
    ssc[tid] = mysum;
    __syncthreads();
    for (int off = 1; off < 1024; off <<= 1) {
        int v = (tid >= off) ? ssc[tid - off] : 0;
        __syncthreads();
        ssc[tid] += v;
        __syncthreads();
    }
    int run = ssc[tid] - mysum;  // exclusive start of my chunk
    for (int j = 0; j < C; j++) {
        int idx = base + j;
        if (idx < n) {
            int c = cnt_cursor[idx];      // read count first
            offsets[idx] = run;
            cnt_cursor[idx] = run;        // becomes the fill cursor
            run += c;
        }
    }
    if (tid == 1023) offsets[n] = ssc[1023];
}

// Scatter edges into dst-sorted order; pack src (16 bits, N<65536) + etype (bits 16..18).
__global__ void k_fill(const int* __restrict__ src, const int* __restrict__ dst,
                       const int* __restrict__ etype, int* cursor,
                       int* __restrict__ edges, int e) {
    int i = blockIdx.x * blockDim.x + threadIdx.x;
    if (i < e) {
        int d = dst[i];
        int pos = atomicAdd(&cursor[d], 1);
        edges[pos] = src[i] | (etype[i] << 16);
    }
}

// One RGCN layer, fused: per 16-node block,
//  phase 1: aggB[nl][b*128+i] = sum over incoming edges of comp[r,b]*x[src,i]  (LDS, 64KB)
//  phase 2: h = aggB @ bases.reshape(1024,128) + bias  (fp32 vector FMA)
template <bool RELU>
__global__ __launch_bounds__(256, 2) void k_layer(
    const float* __restrict__ xin, float* __restrict__ hout,
    const int* __restrict__ edges, const int* __restrict__ offsets,
    const float* __restrict__ comp, const float* __restrict__ bases,
    const float* __restrict__ bias) {
    __shared__ float sA[NB * KDIM];  // exactly 64 KiB
    const int tid = threadIdx.x;
    const int wave = tid >> 6;
    const int lane = tid & 63;

    // ---- phase 1: edge aggregation (one wave per node, 2 dims per lane) ----
    for (int nl = wave; nl < NB; nl += 4) {
        const int n = blockIdx.x * NB + nl;
        float acc[N_BASES][2];
#pragma unroll
        for (int b = 0; b < N_BASES; b++) { acc[b][0] = 0.f; acc[b][1] = 0.f; }
        const int e0 = offsets[n], e1 = offsets[n + 1];
        for (int e = e0; e < e1; ++e) {
            const int pk = edges[e];
            const int s = pk & 0xFFFF;
            const int r = pk >> 16;
            const float2 v = *(const float2*)(xin + (size_t)s * DIM + lane * 2);
            const float4 c0 = *(const float4*)(comp + r * 8);
            const float4 c1 = *(const float4*)(comp + r * 8 + 4);
            const float cw[8] = {c0.x, c0.y, c0.z, c0.w, c1.x, c1.y, c1.z, c1.w};
#pragma unroll
            for (int b = 0; b < 8; b++) {
                acc[b][0] = fmaf(cw[b], v.x, acc[b][0]);
                acc[b][1] = fmaf(cw[b], v.y, acc[b][1]);
            }
        }
#pragma unroll
        for (int b = 0; b < 8; b++) {
            *(float2*)&sA[nl * KDIM + b * DIM + lane * 2] = make_float2(acc[b][0], acc[b][1]);
        }
    }
    __syncthreads();

    // ---- phase 2: [16 x 1024] @ [1024 x 128] ----
    // wave owns o-strip [wave*32, wave*32+32); lane = 2*o_local + kpar (k split in halves of 4)
    const int kpar = lane & 1;
    const int o = wave * 32 + (lane >> 1);
    float acc2[NB];
#pragma unroll
    for (int n = 0; n < NB; n++) acc2[n] = 0.f;
    for (int kk = 0; kk < KDIM; kk += 8) {
        const int k0 = kk + kpar * 4;
        const float w0 = bases[(k0 + 0) * DIM + o];
        const float w1 = bases[(k0 + 1) * DIM + o];
        const float w2 = bases[(k0 + 2) * DIM + o];
        const float w3 = bases[(k0 + 3) * DIM + o];
#pragma unroll
        for (int n = 0; n < NB; n++) {
            const float4 a = *(const float4*)&sA[n * KDIM + k0];
            acc2[n] = fmaf(a.x, w0, fmaf(a.y, w1, fmaf(a.z, w2, fmaf(a.w, w3, acc2[n]))));
        }
    }
#pragma unroll
    for (int n = 0; n < NB; n++) acc2[n] += __shfl_xor(acc2[n], 1, 64);
    const float bo = bias[o];
    const int nbeg = kpar * 8;  // kpar=0 stores nodes 0..7, kpar=1 stores 8..15
#pragma unroll
    for (int j = 0; j < 8; j++) {
        const int n = nbeg + j;
        float hv = acc2[n] + bo;
        if (RELU) hv = fmaxf(hv, 0.f);
        hout[(size_t)(blockIdx.x * NB + n) * DIM + o] = hv;
    }
}

// gate[n] = dot(h3[n,:], gate_w) + gate_b  (one wave per node)
__global__ void k_gate(const float* __restrict__ h3, const float* __restrict__ gw,
                       const float* __restrict__ gb, float* __restrict__ gate, int N) {
    const int n = blockIdx.x * 4 + (threadIdx.x >> 6);
    const int lane = threadIdx.x & 63;
    if (n >= N) return;
    const float2 v = *(const float2*)(h3 + (size_t)n * DIM + lane * 2);
    const float2 g = *(const float2*)(gw + lane * 2);
    float p = v.x * g.x + v.y * g.y;
#pragma unroll
    for (int off = 32; off > 0; off >>= 1) p += __shfl_down(p, off, 64);
    if (lane == 0) gate[n] = p + gb[0];
}

// One block (128 threads) per graph: segment softmax + weighted readout + MLP head + sigmoid.
__global__ __launch_bounds__(128) void k_pool(
    const float* __restrict__ h3, const float* __restrict__ gate, const int* __restrict__ n2g,
    const float* __restrict__ fc1w, const float* __restrict__ fc1b,
    const float* __restrict__ fc2w, const float* __restrict__ fc2b,
    const float* __restrict__ fc3w, const float* __restrict__ fc3b,
    float* __restrict__ out, int N) {
    const int g = blockIdx.x;
    const int tid = threadIdx.x;
    __shared__ float sred[128];
    __shared__ float sr[128];
    __shared__ float sz1[100];
    __shared__ float sz2[64];
    __shared__ float sm, ssum;

    const int s = lower_bound_i(n2g, N, g);
    const int e = lower_bound_i(n2g, N, g + 1);

    // per-graph max
    float m = -3.4e38f;
    for (int n = s + tid; n < e; n += 128) m = fmaxf(m, gate[n]);
    sred[tid] = m;
    __syncthreads();
    for (int off = 64; off > 0; off >>= 1) {
        if (tid < off) sred[tid] = fmaxf(sred[tid], sred[tid + off]);
        __syncthreads();
    }
    if (tid == 0) sm = sred[0];
    __syncthreads();
    const float mm = sm;

    // sum of exp
    float sum = 0.f;
    for (int n = s + tid; n < e; n += 128) sum += expf(gate[n] - mm);
    sred[tid] = sum;
    __syncthreads();
    for (int off = 64; off > 0; off >>= 1) {
        if (tid < off) sred[tid] += sred[tid + off];
        __syncthreads();
    }
    if (tid == 0) ssum = sred[0];
    __syncthreads();
    const float inv = (e > s) ? 1.0f / ssum : 0.f;

    // weighted readout, thread owns dim o = tid
    float acc = 0.f;
    for (int n = s; n < e; ++n) {
        const float wgt = expf(gate[n] - mm);
        acc = fmaf(wgt, h3[(size_t)n * DIM + tid], acc);
    }
    sr[tid] = acc * inv;
    __syncthreads();

    // MLP: 128 -> 100 -> 64 -> 1, relu between, sigmoid at end
    if (tid < 100) {
        float t = fc1b[tid];
        for (int i = 0; i < 128; i++) t = fmaf(sr[i], fc1w[i * 100 + tid], t);
        sz1[tid] = fmaxf(t, 0.f);
    }
    __syncthreads();
    if (tid < 64) {
        float t = fc2b[tid];
        for (int i = 0; i < 100; i++) t = fmaf(sz1[i], fc2w[i * 64 + tid], t);
        sz2[tid] = fmaxf(t, 0.f);
    }
    __syncthreads();
    if (tid < 64) {  // all of wave 0
        float p = sz2[tid] * fc3w[tid];
#pragma unroll
        for (int off = 32; off > 0; off >>= 1) p += __shfl_down(p, off, 64);
        if (tid == 0) {
            const float z = p + fc3b[0];
            out[g] = 1.0f / (1.0f + expf(-z));
        }
    }
}

extern "C" void kernel_launch(void* const* d_in, const int* in_sizes, int n_in,
                              void* d_out, int out_size, void* d_ws, size_t ws_size,
                              hipStream_t stream) {
    (void)in_sizes; (void)n_in; (void)out_size; (void)ws_size;
    const float* features = (const float*)d_in[0];
    const int*   src      = (const int*)d_in[1];
    const int*   dst      = (const int*)d_in[2];
    const int*   etype    = (const int*)d_in[3];
    const int*   n2g      = (const int*)d_in[4];
    const float* bases1   = (const float*)d_in[5];
    const float* comp1    = (const float*)d_in[6];
    const float* bias1    = (const float*)d_in[7];
    const float* bases2   = (const float*)d_in[8];
    const float* comp2    = (const float*)d_in[9];
    const float* bias2    = (const float*)d_in[10];
    const float* bases3   = (const float*)d_in[11];
    const float* comp3    = (const float*)d_in[12];
    const float* bias3    = (const float*)d_in[13];
    const float* gate_w   = (const float*)d_in[14];
    const float* gate_b   = (const float*)d_in[15];
    const float* fc1w     = (const float*)d_in[16];
    const float* fc1b     = (const float*)d_in[17];
    const float* fc2w     = (const float*)d_in[18];
    const float* fc2b     = (const float*)d_in[19];
    const float* fc3w     = (const float*)d_in[20];
    const float* fc3b     = (const float*)d_in[21];
    float* out = (float*)d_out;

    // workspace layout (256B aligned): ~54 MB total
    char* w = (char*)d_ws;
    auto alloc = [&](size_t bytes) -> char* {
        char* p = w;
        w += (bytes + 255) & ~(size_t)255;
        return p;
    };
    int*   offsets = (int*)alloc((N_NODES + 1) * sizeof(int));
    int*   cursor  = (int*)alloc(N_NODES * sizeof(int));        // counts, then fill cursor
    int*   edges   = (int*)alloc(N_EDGES * sizeof(int));
    float* hA      = (float*)alloc((size_t)N_NODES * DIM * sizeof(float));
    float* hB      = (float*)alloc((size_t)N_NODES * DIM * sizeof(float));
    float* gate    = (float*)alloc(N_NODES * sizeof(float));

    // CSR by dst (rebuilt every call; ws is re-poisoned by the harness)
    k_zero_i<<<(N_NODES + 255) / 256, 256, 0, stream>>>(cursor, N_NODES);
    k_count<<<(N_EDGES + 255) / 256, 256, 0, stream>>>(dst, cursor, N_EDGES);
    k_scan<<<1, 1024, 0, stream>>>(cursor, offsets, N_NODES);
    k_fill<<<(N_EDGES + 255) / 256, 256, 0, stream>>>(src, dst, etype, cursor, edges, N_EDGES);

    // 3 RGCN layers (aggregate-first + fused GEMM)
    k_layer<true><<<N_NODES / NB, 256, 0, stream>>>(features, hA, edges, offsets, comp1, bases1, bias1);
    k_layer<true><<<N_NODES / NB, 256, 0, stream>>>(hA, hB, edges, offsets, comp2, bases2, bias2);
    k_layer<false><<<N_NODES / NB, 256, 0, stream>>>(hB, hA, edges, offsets, comp3, bases3, bias3);

    // attention gate + pooling + MLP head
    k_gate<<<N_NODES / 4, 256, 0, stream>>>(hA, gate_w, gate_b, gate, N_NODES);
    k_pool<<<N_GRAPHS, 128, 0, stream>>>(hA, gate, n2g, fc1w, fc1b, fc2w, fc2b, fc3w, fc3b, out, N_NODES);
}

// Round 2
// 1296.342 us; speedup vs baseline: 1.3565x; 1.3565x over previous
//
#include <hip/hip_runtime.h>
#include <hip/hip_bf16.h>
#include <math.h>

#define N_NODES 50000
#define N_EDGES 600000
#define DIM 128
#define N_REL 8
#define N_BASES 8
#define N_GRAPHS 256
#define NB 16                 // nodes per block in layer kernel (50000 = 3125*16 exact)
#define KDIM (N_BASES * DIM)  // 1024

typedef __attribute__((ext_vector_type(8))) short short8;
typedef __attribute__((ext_vector_type(4))) float floatx4;
typedef unsigned int uint;
typedef unsigned short ushort;

static __device__ __forceinline__ int lower_bound_i(const int* a, int n, int v) {
    int lo = 0, hi = n;
    while (lo < hi) { int mid = (lo + hi) >> 1; if (a[mid] < v) lo = mid + 1; else hi = mid; }
    return lo;
}

// RNE float->bf16 split helpers. Returns packed (hiword, loword) for a pair (x,y):
// hiword = bf16(x) | bf16(y)<<16 ; loword = bf16(x-hi(x)) | bf16(y-hi(y))<<16
static __device__ __forceinline__ uint2 split2(float x, float y) {
    uint ux = __float_as_uint(x);
    uint hx = (ux + 0x7FFFu + ((ux >> 16) & 1u)) & 0xFFFF0000u;
    float rx = x - __uint_as_float(hx);
    uint urx = __float_as_uint(rx);
    uint lx = (urx + 0x7FFFu + ((urx >> 16) & 1u)) >> 16;
    uint uy = __float_as_uint(y);
    uint hy = (uy + 0x7FFFu + ((uy >> 16) & 1u)) & 0xFFFF0000u;
    float ry = y - __uint_as_float(hy);
    uint ury = __float_as_uint(ry);
    uint ly = (ury + 0x7FFFu + ((ury >> 16) & 1u)) >> 16;
    return make_uint2((hx >> 16) | (hy & 0xFFFF0000u), lx | (ly << 16));
}

__global__ void k_zero_i(int* p, int n) {
    int i = blockIdx.x * blockDim.x + threadIdx.x;
    if (i < n) p[i] = 0;
}

__global__ void k_count(const int* __restrict__ dst, int* __restrict__ counts, int e) {
    int i = blockIdx.x * blockDim.x + threadIdx.x;
    if (i < e) atomicAdd(&counts[dst[i]], 1);
}

__global__ __launch_bounds__(1024) void k_scan(int* cnt_cursor, int* __restrict__ offsets, int n) {
    const int tid = threadIdx.x;
    const int C = (n + 1023) >> 10;
    __shared__ int ssc[1024];
    const int base = tid * C;
    int mysum = 0;
    for (int j = 0; j < C; j++) { int idx = base + j; if (idx < n) mysum += cnt_cursor[idx]; }
    ssc[tid] = mysum;
    __syncthreads();
    for (int off = 1; off < 1024; off <<= 1) {
        int v = (tid >= off) ? ssc[tid - off] : 0;
        __syncthreads();
        ssc[tid] += v;
        __syncthreads();
    }
    int run = ssc[tid] - mysum;
    for (int j = 0; j < C; j++) {
        int idx = base + j;
        if (idx < n) {
            int c = cnt_cursor[idx];
            offsets[idx] = run;
            cnt_cursor[idx] = run;
            run += c;
        }
    }
    if (tid == 1023) offsets[n] = ssc[1023];
}

__global__ void k_fill(const int* __restrict__ src, const int* __restrict__ dst,
                       const int* __restrict__ etype, int* cursor,
                       int* __restrict__ edges, int e) {
    int i = blockIdx.x * blockDim.x + threadIdx.x;
    if (i < e) {
        int d = dst[i];
        int pos = atomicAdd(&cursor[d], 1);
        edges[pos] = src[i] | (etype[i] << 16);
    }
}

// Pack bases [K=1024][N=128] fp32 into MFMA-B-fragment-ordered bf16 hi/lo:
// layout [kt:32][n:128][kk:32] ushort; lane (q,mm) reads 8 contiguous at n*32+q*8.
__global__ void k_packB(const float* __restrict__ bases, ushort* __restrict__ Bhi,
                        ushort* __restrict__ Blo) {
    int id = blockIdx.x * blockDim.x + threadIdx.x;  // 131072
    int n = id & 127, k = id >> 7;
    float v = bases[(size_t)k * DIM + n];
    uint u = __float_as_uint(v);
    uint hu = (u + 0x7FFFu + ((u >> 16) & 1u)) & 0xFFFF0000u;
    float rf = v - __uint_as_float(hu);
    uint ur = __float_as_uint(rf);
    uint lu = (ur + 0x7FFFu + ((ur >> 16) & 1u)) >> 16;
    int kt = k >> 5, kk = k & 31;
    int off = kt * 4096 + n * 32 + kk;
    Bhi[off] = (ushort)(hu >> 16);
    Blo[off] = (ushort)lu;
}

// One RGCN layer, fused:
//  phase 1: aggregate incoming edges into basis space, write bf16 hi/lo into
//           MFMA-packed swizzled LDS (chunk = q*16 + (m^q), 16B chunks).
//  phase 2: [16 x 1024] @ [1024 x 128] via mfma_f32_16x16x32_bf16, 3-term split.
template <bool RELU>
__global__ __launch_bounds__(256, 2) void k_layer(
    const float* __restrict__ xin, float* __restrict__ hout,
    const int* __restrict__ edges, const int* __restrict__ offsets,
    const float* __restrict__ comp,
    const ushort* __restrict__ Bhi, const ushort* __restrict__ Blo,
    const float* __restrict__ bias) {
    __shared__ ushort sHi[NB * KDIM];  // 32 KiB
    __shared__ ushort sLo[NB * KDIM];  // 32 KiB
    const int tid = threadIdx.x;
    const int w = tid >> 6;
    const int lane = tid & 63;

    // ---- phase 1: edge aggregation (one wave per node, 2 dims per lane) ----
    {
        const int kt_base = lane >> 4;        // within-b kt sub-index
        const int q2 = (lane & 15) >> 2;      // k-quad of this lane's dim pair
        const int jw = lane & 3;              // 32-bit word index within 16B chunk
        for (int nl = w; nl < NB; nl += 4) {
            const int n = blockIdx.x * NB + nl;
            float2 acc[N_BASES];
#pragma unroll
            for (int b = 0; b < N_BASES; b++) acc[b] = make_float2(0.f, 0.f);
            const int e0 = offsets[n], e1 = offsets[n + 1];
            for (int e = e0; e < e1; ++e) {
                const int pk = edges[e];
                const int s = pk & 0xFFFF;
                const int r = pk >> 16;
                const float2 v = *(const float2*)(xin + (size_t)s * DIM + lane * 2);
                const float4 c0 = *(const float4*)(comp + r * 8);
                const float4 c1 = *(const float4*)(comp + r * 8 + 4);
                const float cw[8] = {c0.x, c0.y, c0.z, c0.w, c1.x, c1.y, c1.z, c1.w};
#pragma unroll
                for (int b = 0; b < 8; b++) {
                    acc[b].x = fmaf(cw[b], v.x, acc[b].x);
                    acc[b].y = fmaf(cw[b], v.y, acc[b].y);
                }
            }
            const int chunk = q2 * 16 + (nl ^ q2);
#pragma unroll
            for (int b = 0; b < 8; b++) {
                const int kt = b * 4 + kt_base;
                const int woff = kt * 256 + chunk * 4 + jw;  // 32-bit word offset
                const uint2 p = split2(acc[b].x, acc[b].y);
                ((uint*)sHi)[woff] = p.x;
                ((uint*)sLo)[woff] = p.y;
            }
        }
    }
    __syncthreads();

    // ---- phase 2: MFMA GEMM, wave owns 32-col strip (two 16-wide n-tiles) ----
    const int q = lane >> 4, mm = lane & 15;
    const int a_off = (q * 16 + (mm ^ q)) * 8;  // ushort offset of A chunk within ktile
    const int n0 = w * 32 + mm, n1 = n0 + 16;
    floatx4 acc0 = {0.f, 0.f, 0.f, 0.f};
    floatx4 acc1 = {0.f, 0.f, 0.f, 0.f};
    for (int kt = 0; kt < 32; ++kt) {
        const short8 ah = *(const short8*)(sHi + kt * 512 + a_off);
        const short8 al = *(const short8*)(sLo + kt * 512 + a_off);
        const short8 bh0 = *(const short8*)(Bhi + kt * 4096 + n0 * 32 + q * 8);
        const short8 bl0 = *(const short8*)(Blo + kt * 4096 + n0 * 32 + q * 8);
        const short8 bh1 = *(const short8*)(Bhi + kt * 4096 + n1 * 32 + q * 8);
        const short8 bl1 = *(const short8*)(Blo + kt * 4096 + n1 * 32 + q * 8);
        acc0 = __builtin_amdgcn_mfma_f32_16x16x32_bf16(ah, bh0, acc0, 0, 0, 0);
        acc1 = __builtin_amdgcn_mfma_f32_16x16x32_bf16(ah, bh1, acc1, 0, 0, 0);
        acc0 = __builtin_amdgcn_mfma_f32_16x16x32_bf16(ah, bl0, acc0, 0, 0, 0);
        acc1 = __builtin_amdgcn_mfma_f32_16x16x32_bf16(ah, bl1, acc1, 0, 0, 0);
        acc0 = __builtin_amdgcn_mfma_f32_16x16x32_bf16(al, bh0, acc0, 0, 0, 0);
        acc1 = __builtin_amdgcn_mfma_f32_16x16x32_bf16(al, bh1, acc1, 0, 0, 0);
    }
    const float b0 = bias[n0], b1 = bias[n1];
#pragma unroll
    for (int r = 0; r < 4; r++) {
        const int node = blockIdx.x * NB + q * 4 + r;  // C/D: row=(lane>>4)*4+reg, col=lane&15
        float v0 = acc0[r] + b0;
        float v1 = acc1[r] + b1;
        if (RELU) { v0 = fmaxf(v0, 0.f); v1 = fmaxf(v1, 0.f); }
        hout[(size_t)node * DIM + n0] = v0;
        hout[(size_t)node * DIM + n1] = v1;
    }
}

// gate[n] = dot(h3[n,:], gate_w) + gate_b  (one wave per node)
__global__ void k_gate(const float* __restrict__ h3, const float* __restrict__ gw,
                       const float* __restrict__ gb, float* __restrict__ gate, int N) {
    const int n = blockIdx.x * 4 + (threadIdx.x >> 6);
    const int lane = threadIdx.x & 63;
    if (n >= N) return;
    const float2 v = *(const float2*)(h3 + (size_t)n * DIM + lane * 2);
    const float2 g = *(const float2*)(gw + lane * 2);
    float p = v.x * g.x + v.y * g.y;
#pragma unroll
    for (int off = 32; off > 0; off >>= 1) p += __shfl_down(p, off, 64);
    if (lane == 0) gate[n] = p + gb[0];
}

// One block (128 threads) per graph: segment softmax + weighted readout + MLP head + sigmoid.
__global__ __launch_bounds__(128) void k_pool(
    const float* __restrict__ h3, const float* __restrict__ gate, const int* __restrict__ n2g,
    const float* __restrict__ fc1w, const float* __restrict__ fc1b,
    const float* __restrict__ fc2w, const float* __restrict__ fc2b,
    const float* __restrict__ fc3w, const float* __restrict__ fc3b,
    float* __restrict__ out, int N) {
    const int g = blockIdx.x;
    const int tid = threadIdx.x;
    __shared__ float sred[128];
    __shared__ float sr[128];
    __shared__ float sz1[100];
    __shared__ float sz2[64];
    __shared__ float sm, ssum;

    const int s = lower_bound_i(n2g, N, g);
    const int e = lower_bound_i(n2g, N, g + 1);

    float m = -3.4e38f;
    for (int n = s + tid; n < e; n += 128) m = fmaxf(m, gate[n]);
    sred[tid] = m;
    __syncthreads();
    for (int off = 64; off > 0; off >>= 1) {
        if (tid < off) sred[tid] = fmaxf(sred[tid], sred[tid + off]);
        __syncthreads();
    }
    if (tid == 0) sm = sred[0];
    __syncthreads();
    const float mm = sm;

    float sum = 0.f;
    for (int n = s + tid; n < e; n += 128) sum += expf(gate[n] - mm);
    sred[tid] = sum;
    __syncthreads();
    for (int off = 64; off > 0; off >>= 1) {
        if (tid < off) sred[tid] += sred[tid + off];
        __syncthreads();
    }
    if (tid == 0) ssum = sred[0];
    __syncthreads();
    const float inv = (e > s) ? 1.0f / ssum : 0.f;

    float acc = 0.f;
    for (int n = s; n < e; ++n) {
        const float wgt = expf(gate[n] - mm);
        acc = fmaf(wgt, h3[(size_t)n * DIM + tid], acc);
    }
    sr[tid] = acc * inv;
    __syncthreads();

    if (tid < 100) {
        float t = fc1b[tid];
        for (int i = 0; i < 128; i++) t = fmaf(sr[i], fc1w[i * 100 + tid], t);
        sz1[tid] = fmaxf(t, 0.f);
    }
    __syncthreads();
    if (tid < 64) {
        float t = fc2b[tid];
        for (int i = 0; i < 100; i++) t = fmaf(sz1[i], fc2w[i * 64 + tid], t);
        sz2[tid] = fmaxf(t, 0.f);
    }
    __syncthreads();
    if (tid < 64) {
        float p = sz2[tid] * fc3w[tid];
#pragma unroll
        for (int off = 32; off > 0; off >>= 1) p += __shfl_down(p, off, 64);
        if (tid == 0) {
            const float z = p + fc3b[0];
            out[g] = 1.0f / (1.0f + expf(-z));
        }
    }
}

extern "C" void kernel_launch(void* const* d_in, const int* in_sizes, int n_in,
                              void* d_out, int out_size, void* d_ws, size_t ws_size,
                              hipStream_t stream) {
    (void)in_sizes; (void)n_in; (void)out_size; (void)ws_size;
    const float* features = (const float*)d_in[0];
    const int*   src      = (const int*)d_in[1];
    const int*   dst      = (const int*)d_in[2];
    const int*   etype    = (const int*)d_in[3];
    const int*   n2g      = (const int*)d_in[4];
    const float* bases1   = (const float*)d_in[5];
    const float* comp1    = (const float*)d_in[6];
    const float* bias1    = (const float*)d_in[7];
    const float* bases2   = (const float*)d_in[8];
    const float* comp2    = (const float*)d_in[9];
    const float* bias2    = (const float*)d_in[10];
    const float* bases3   = (const float*)d_in[11];
    const float* comp3    = (const float*)d_in[12];
    const float* bias3    = (const float*)d_in[13];
    const float* gate_w   = (const float*)d_in[14];
    const float* gate_b   = (const float*)d_in[15];
    const float* fc1w     = (const float*)d_in[16];
    const float* fc1b     = (const float*)d_in[17];
    const float* fc2w     = (const float*)d_in[18];
    const float* fc2b     = (const float*)d_in[19];
    const float* fc3w     = (const float*)d_in[20];
    const float* fc3b     = (const float*)d_in[21];
    float* out = (float*)d_out;

    char* w = (char*)d_ws;
    auto alloc = [&](size_t bytes) -> char* {
        char* p = w;
        w += (bytes + 255) & ~(size_t)255;
        return p;
    };
    int*    offsets = (int*)alloc((N_NODES + 1) * sizeof(int));
    int*    cursor  = (int*)alloc(N_NODES * sizeof(int));
    int*    edges   = (int*)alloc(N_EDGES * sizeof(int));
    float*  hA      = (float*)alloc((size_t)N_NODES * DIM * sizeof(float));
    float*  hB      = (float*)alloc((size_t)N_NODES * DIM * sizeof(float));
    float*  gate    = (float*)alloc(N_NODES * sizeof(float));
    ushort* Bhi1    = (ushort*)alloc((size_t)KDIM * DIM * sizeof(ushort));
    ushort* Blo1    = (ushort*)alloc((size_t)KDIM * DIM * sizeof(ushort));
    ushort* Bhi2    = (ushort*)alloc((size_t)KDIM * DIM * sizeof(ushort));
    ushort* Blo2    = (ushort*)alloc((size_t)KDIM * DIM * sizeof(ushort));
    ushort* Bhi3    = (ushort*)alloc((size_t)KDIM * DIM * sizeof(ushort));
    ushort* Blo3    = (ushort*)alloc((size_t)KDIM * DIM * sizeof(ushort));

    // weight packing (bf16 hi/lo, MFMA fragment order)
    k_packB<<<(KDIM * DIM) / 256, 256, 0, stream>>>(bases1, Bhi1, Blo1);
    k_packB<<<(KDIM * DIM) / 256, 256, 0, stream>>>(bases2, Bhi2, Blo2);
    k_packB<<<(KDIM * DIM) / 256, 256, 0, stream>>>(bases3, Bhi3, Blo3);

    // CSR by dst (rebuilt every call)
    k_zero_i<<<(N_NODES + 255) / 256, 256, 0, stream>>>(cursor, N_NODES);
    k_count<<<(N_EDGES + 255) / 256, 256, 0, stream>>>(dst, cursor, N_EDGES);
    k_scan<<<1, 1024, 0, stream>>>(cursor, offsets, N_NODES);
    k_fill<<<(N_EDGES + 255) / 256, 256, 0, stream>>>(src, dst, etype, cursor, edges, N_EDGES);

    // 3 RGCN layers (aggregate-first + fused MFMA GEMM)
    k_layer<true><<<N_NODES / NB, 256, 0, stream>>>(features, hA, edges, offsets, comp1, Bhi1, Blo1, bias1);
    k_layer<true><<<N_NODES / NB, 256, 0, stream>>>(hA, hB, edges, offsets, comp2, Bhi2, Blo2, bias2);
    k_layer<false><<<N_NODES / NB, 256, 0, stream>>>(hB, hA, edges, offsets, comp3, Bhi3, Blo3, bias3);

    // attention gate + pooling + MLP head
    k_gate<<<N_NODES / 4, 256, 0, stream>>>(hA, gate_w, gate_b, gate, N_NODES);
    k_pool<<<N_GRAPHS, 128, 0, stream>>>(hA, gate, n2g, fc1w, fc1b, fc2w, fc2b, fc3w, fc3b, out, N_NODES);
}

// Round 4
// 1000.880 us; speedup vs baseline: 1.7570x; 1.2952x over previous
//
#include <hip/hip_runtime.h>
#include <hip/hip_bf16.h>
#include <math.h>

#define N_NODES 50000
#define N_EDGES 600000
#define DIM 128
#define N_REL 8
#define N_BASES 8
#define N_GRAPHS 256
#define NB 16                 // nodes per block in layer kernel (50000 = 3125*16 exact)
#define KDIM (N_BASES * DIM)  // 1024

typedef __attribute__((ext_vector_type(8))) short short8;
typedef __attribute__((ext_vector_type(4))) float floatx4;
typedef __attribute__((ext_vector_type(2))) float f32x2;
typedef unsigned int uint;
typedef unsigned short ushort;

static __device__ __forceinline__ int lower_bound_i(const int* a, int n, int v) {
    int lo = 0, hi = n;
    while (lo < hi) { int mid = (lo + hi) >> 1; if (a[mid] < v) lo = mid + 1; else hi = mid; }
    return lo;
}

// RNE float->bf16 split helpers. Returns packed (hiword, loword) for a pair (x,y):
// hiword = bf16(x) | bf16(y)<<16 ; loword = bf16(x-hi(x)) | bf16(y-hi(y))<<16
static __device__ __forceinline__ uint2 split2(float x, float y) {
    uint ux = __float_as_uint(x);
    uint hx = (ux + 0x7FFFu + ((ux >> 16) & 1u)) & 0xFFFF0000u;
    float rx = x - __uint_as_float(hx);
    uint urx = __float_as_uint(rx);
    uint lx = (urx + 0x7FFFu + ((urx >> 16) & 1u)) >> 16;
    uint uy = __float_as_uint(y);
    uint hy = (uy + 0x7FFFu + ((uy >> 16) & 1u)) & 0xFFFF0000u;
    float ry = y - __uint_as_float(hy);
    uint ury = __float_as_uint(ry);
    uint ly = (ury + 0x7FFFu + ((ury >> 16) & 1u)) >> 16;
    return make_uint2((hx >> 16) | (hy & 0xFFFF0000u), lx | (ly << 16));
}

__global__ void k_zero_i(int* p, int n) {
    int i = blockIdx.x * blockDim.x + threadIdx.x;
    if (i < n) p[i] = 0;
}

__global__ void k_count(const int* __restrict__ dst, int* __restrict__ counts, int e) {
    int i = blockIdx.x * blockDim.x + threadIdx.x;
    if (i < e) atomicAdd(&counts[dst[i]], 1);
}

__global__ __launch_bounds__(1024) void k_scan(int* cnt_cursor, int* __restrict__ offsets, int n) {
    const int tid = threadIdx.x;
    const int C = (n + 1023) >> 10;
    __shared__ int ssc[1024];
    const int base = tid * C;
    int mysum = 0;
    for (int j = 0; j < C; j++) { int idx = base + j; if (idx < n) mysum += cnt_cursor[idx]; }
    ssc[tid] = mysum;
    __syncthreads();
    for (int off = 1; off < 1024; off <<= 1) {
        int v = (tid >= off) ? ssc[tid - off] : 0;
        __syncthreads();
        ssc[tid] += v;
        __syncthreads();
    }
    int run = ssc[tid] - mysum;
    for (int j = 0; j < C; j++) {
        int idx = base + j;
        if (idx < n) {
            int c = cnt_cursor[idx];
            offsets[idx] = run;
            cnt_cursor[idx] = run;
            run += c;
        }
    }
    if (tid == 1023) offsets[n] = ssc[1023];
}

__global__ void k_fill(const int* __restrict__ src, const int* __restrict__ dst,
                       const int* __restrict__ etype, int* cursor,
                       int* __restrict__ edges, int e) {
    int i = blockIdx.x * blockDim.x + threadIdx.x;
    if (i < e) {
        int d = dst[i];
        int pos = atomicAdd(&cursor[d], 1);
        edges[pos] = src[i] | (etype[i] << 16);
    }
}

// Pack bases [K=1024][N=128] fp32 into MFMA-B-fragment-ordered bf16 hi/lo:
// layout [kt:32][n:128][kk:32] ushort; lane (q,mm) reads 8 contiguous at n*32+q*8.
__global__ void k_packB(const float* __restrict__ bases, ushort* __restrict__ Bhi,
                        ushort* __restrict__ Blo) {
    int id = blockIdx.x * blockDim.x + threadIdx.x;  // 131072
    int n = id & 127, k = id >> 7;
    float v = bases[(size_t)k * DIM + n];
    uint u = __float_as_uint(v);
    uint hu = (u + 0x7FFFu + ((u >> 16) & 1u)) & 0xFFFF0000u;
    float rf = v - __uint_as_float(hu);
    uint ur = __float_as_uint(rf);
    uint lu = (ur + 0x7FFFu + ((ur >> 16) & 1u)) >> 16;
    int kt = k >> 5, kk = k & 31;
    int off = kt * 4096 + n * 32 + kk;
    Bhi[off] = (ushort)(hu >> 16);
    Blo[off] = (ushort)lu;
}

// One RGCN layer, fused:
//  phase 1: aggregate incoming edges into basis space (4-deep batched gathers,
//           packed f32x2 FMA), write bf16 hi/lo into MFMA-packed swizzled LDS.
//  phase 2: [16 x 1024] @ [1024 x 128] via mfma_f32_16x16x32_bf16, 3-term split.
//
// PITFALL (R3): do NOT scalarize the edge loop (readfirstlane on nl/e0/e1).
// Provably-uniform addresses let the compiler promote edges[]/offsets[] loads
// to s_load through the scalar cache; edges[] is rebuilt with a different
// atomic ordering every call, and stale scalar-cache lines mix orderings
// across calls -> duplicated/dropped edges -> wrong output on replay.
// Per-lane VGPR addressing (tid-derived, divergence analysis can't prove
// uniform) keeps these on the vector path, which is coherent. [R2 passed,
// R3 failed the replay tripwire with exactly this delta.]
template <bool RELU>
__global__ __launch_bounds__(256, 2) void k_layer(
    const float* __restrict__ xin, float* __restrict__ hout,
    const int* __restrict__ edges, const int* __restrict__ offsets,
    const float* __restrict__ comp,
    const ushort* __restrict__ Bhi, const ushort* __restrict__ Blo,
    const float* __restrict__ bias) {
    __shared__ ushort sHi[NB * KDIM];  // 32 KiB
    __shared__ ushort sLo[NB * KDIM];  // 32 KiB
    const int tid = threadIdx.x;
    const int w = tid >> 6;
    const int lane = tid & 63;

    // ---- phase 1: edge aggregation (one wave per node, 2 dims per lane) ----
    {
        const int kt_base = lane >> 4;
        const int q2 = (lane & 15) >> 2;
        const int jw = lane & 3;
        const int lane2 = lane * 2;  // dim pair base
        for (int nl = w; nl < NB; nl += 4) {
            const int n = blockIdx.x * NB + nl;
            f32x2 acc[N_BASES];
#pragma unroll
            for (int b = 0; b < N_BASES; b++) acc[b] = (f32x2)0.f;
            const int e0 = offsets[n], e1 = offsets[n + 1];
            int e = e0;
            // 4-deep batched edges: 4 outstanding x-row gathers for latency hiding.
            for (; e + 4 <= e1; e += 4) {
                const int pk0 = edges[e + 0];
                const int pk1 = edges[e + 1];
                const int pk2 = edges[e + 2];
                const int pk3 = edges[e + 3];
                const f32x2 v0 = *(const f32x2*)(xin + (size_t)(pk0 & 0xFFFF) * DIM + lane2);
                const f32x2 v1 = *(const f32x2*)(xin + (size_t)(pk1 & 0xFFFF) * DIM + lane2);
                const f32x2 v2 = *(const f32x2*)(xin + (size_t)(pk2 & 0xFFFF) * DIM + lane2);
                const f32x2 v3 = *(const f32x2*)(xin + (size_t)(pk3 & 0xFFFF) * DIM + lane2);
                const float4 c00 = *(const float4*)(comp + ((pk0 >> 16) << 3));
                const float4 c01 = *(const float4*)(comp + ((pk0 >> 16) << 3) + 4);
                const float4 c10 = *(const float4*)(comp + ((pk1 >> 16) << 3));
                const float4 c11 = *(const float4*)(comp + ((pk1 >> 16) << 3) + 4);
                const float4 c20 = *(const float4*)(comp + ((pk2 >> 16) << 3));
                const float4 c21 = *(const float4*)(comp + ((pk2 >> 16) << 3) + 4);
                const float4 c30 = *(const float4*)(comp + ((pk3 >> 16) << 3));
                const float4 c31 = *(const float4*)(comp + ((pk3 >> 16) << 3) + 4);
                const float cw0[8] = {c00.x, c00.y, c00.z, c00.w, c01.x, c01.y, c01.z, c01.w};
                const float cw1[8] = {c10.x, c10.y, c10.z, c10.w, c11.x, c11.y, c11.z, c11.w};
                const float cw2[8] = {c20.x, c20.y, c20.z, c20.w, c21.x, c21.y, c21.z, c21.w};
                const float cw3[8] = {c30.x, c30.y, c30.z, c30.w, c31.x, c31.y, c31.z, c31.w};
#pragma unroll
                for (int b = 0; b < 8; b++) {
                    acc[b] = __builtin_elementwise_fma((f32x2)cw0[b], v0, acc[b]);
                    acc[b] = __builtin_elementwise_fma((f32x2)cw1[b], v1, acc[b]);
                    acc[b] = __builtin_elementwise_fma((f32x2)cw2[b], v2, acc[b]);
                    acc[b] = __builtin_elementwise_fma((f32x2)cw3[b], v3, acc[b]);
                }
            }
            for (; e < e1; ++e) {
                const int pk = edges[e];
                const f32x2 v = *(const f32x2*)(xin + (size_t)(pk & 0xFFFF) * DIM + lane2);
                const float4 c0 = *(const float4*)(comp + ((pk >> 16) << 3));
                const float4 c1 = *(const float4*)(comp + ((pk >> 16) << 3) + 4);
                const float cw[8] = {c0.x, c0.y, c0.z, c0.w, c1.x, c1.y, c1.z, c1.w};
#pragma unroll
                for (int b = 0; b < 8; b++) acc[b] = __builtin_elementwise_fma((f32x2)cw[b], v, acc[b]);
            }
            const int chunk = q2 * 16 + (nl ^ q2);
#pragma unroll
            for (int b = 0; b < 8; b++) {
                const int kt = b * 4 + kt_base;
                const int woff = kt * 256 + chunk * 4 + jw;  // 32-bit word offset
                const uint2 p = split2(acc[b].x, acc[b].y);
                ((uint*)sHi)[woff] = p.x;
                ((uint*)sLo)[woff] = p.y;
            }
        }
    }
    __syncthreads();

    // ---- phase 2: MFMA GEMM, wave owns 32-col strip (two 16-wide n-tiles) ----
    const int q = lane >> 4, mm = lane & 15;
    const int a_off = (q * 16 + (mm ^ q)) * 8;  // ushort offset of A chunk within ktile
    const int n0 = w * 32 + mm, n1 = n0 + 16;
    floatx4 acc0 = {0.f, 0.f, 0.f, 0.f};
    floatx4 acc1 = {0.f, 0.f, 0.f, 0.f};
    for (int kt = 0; kt < 32; ++kt) {
        const short8 ah = *(const short8*)(sHi + kt * 512 + a_off);
        const short8 al = *(const short8*)(sLo + kt * 512 + a_off);
        const short8 bh0 = *(const short8*)(Bhi + kt * 4096 + n0 * 32 + q * 8);
        const short8 bl0 = *(const short8*)(Blo + kt * 4096 + n0 * 32 + q * 8);
        const short8 bh1 = *(const short8*)(Bhi + kt * 4096 + n1 * 32 + q * 8);
        const short8 bl1 = *(const short8*)(Blo + kt * 4096 + n1 * 32 + q * 8);
        acc0 = __builtin_amdgcn_mfma_f32_16x16x32_bf16(ah, bh0, acc0, 0, 0, 0);
        acc1 = __builtin_amdgcn_mfma_f32_16x16x32_bf16(ah, bh1, acc1, 0, 0, 0);
        acc0 = __builtin_amdgcn_mfma_f32_16x16x32_bf16(ah, bl0, acc0, 0, 0, 0);
        acc1 = __builtin_amdgcn_mfma_f32_16x16x32_bf16(ah, bl1, acc1, 0, 0, 0);
        acc0 = __builtin_amdgcn_mfma_f32_16x16x32_bf16(al, bh0, acc0, 0, 0, 0);
        acc1 = __builtin_amdgcn_mfma_f32_16x16x32_bf16(al, bh1, acc1, 0, 0, 0);
    }
    const float b0 = bias[n0], b1 = bias[n1];
#pragma unroll
    for (int r = 0; r < 4; r++) {
        const int node = blockIdx.x * NB + q * 4 + r;  // C/D: row=(lane>>4)*4+reg, col=lane&15
        float v0 = acc0[r] + b0;
        float v1 = acc1[r] + b1;
        if (RELU) { v0 = fmaxf(v0, 0.f); v1 = fmaxf(v1, 0.f); }
        hout[(size_t)node * DIM + n0] = v0;
        hout[(size_t)node * DIM + n1] = v1;
    }
}

// gate[n] = dot(h3[n,:], gate_w) + gate_b  (one wave per node)
__global__ void k_gate(const float* __restrict__ h3, const float* __restrict__ gw,
                       const float* __restrict__ gb, float* __restrict__ gate, int N) {
    const int n = blockIdx.x * 4 + (threadIdx.x >> 6);
    const int lane = threadIdx.x & 63;
    if (n >= N) return;
    const float2 v = *(const float2*)(h3 + (size_t)n * DIM + lane * 2);
    const float2 g = *(const float2*)(gw + lane * 2);
    float p = v.x * g.x + v.y * g.y;
#pragma unroll
    for (int off = 32; off > 0; off >>= 1) p += __shfl_down(p, off, 64);
    if (lane == 0) gate[n] = p + gb[0];
}

// One block (128 threads) per graph: segment softmax + weighted readout + MLP head + sigmoid.
__global__ __launch_bounds__(128) void k_pool(
    const float* __restrict__ h3, const float* __restrict__ gate, const int* __restrict__ n2g,
    const float* __restrict__ fc1w, const float* __restrict__ fc1b,
    const float* __restrict__ fc2w, const float* __restrict__ fc2b,
    const float* __restrict__ fc3w, const float* __restrict__ fc3b,
    float* __restrict__ out, int N) {
    const int g = blockIdx.x;
    const int tid = threadIdx.x;
    __shared__ float sred[128];
    __shared__ float sr[128];
    __shared__ float sz1[100];
    __shared__ float sz2[64];
    __shared__ float sm, ssum;

    const int s = lower_bound_i(n2g, N, g);
    const int e = lower_bound_i(n2g, N, g + 1);

    float m = -3.4e38f;
    for (int n = s + tid; n < e; n += 128) m = fmaxf(m, gate[n]);
    sred[tid] = m;
    __syncthreads();
    for (int off = 64; off > 0; off >>= 1) {
        if (tid < off) sred[tid] = fmaxf(sred[tid], sred[tid + off]);
        __syncthreads();
    }
    if (tid == 0) sm = sred[0];
    __syncthreads();
    const float mm = sm;

    float sum = 0.f;
    for (int n = s + tid; n < e; n += 128) sum += expf(gate[n] - mm);
    sred[tid] = sum;
    __syncthreads();
    for (int off = 64; off > 0; off >>= 1) {
        if (tid < off) sred[tid] += sred[tid + off];
        __syncthreads();
    }
    if (tid == 0) ssum = sred[0];
    __syncthreads();
    const float inv = (e > s) ? 1.0f / ssum : 0.f;

    // weighted readout, thread owns dim o = tid; node loop unrolled x4
    float acc = 0.f;
    int n = s;
    for (; n + 4 <= e; n += 4) {
        const float w0 = expf(gate[n + 0] - mm);
        const float w1 = expf(gate[n + 1] - mm);
        const float w2 = expf(gate[n + 2] - mm);
        const float w3 = expf(gate[n + 3] - mm);
        const float a0 = h3[(size_t)(n + 0) * DIM + tid];
        const float a1 = h3[(size_t)(n + 1) * DIM + tid];
        const float a2 = h3[(size_t)(n + 2) * DIM + tid];
        const float a3 = h3[(size_t)(n + 3) * DIM + tid];
        acc = fmaf(w0, a0, acc);
        acc = fmaf(w1, a1, acc);
        acc = fmaf(w2, a2, acc);
        acc = fmaf(w3, a3, acc);
    }
    for (; n < e; ++n) {
        const float wgt = expf(gate[n] - mm);
        acc = fmaf(wgt, h3[(size_t)n * DIM + tid], acc);
    }
    sr[tid] = acc * inv;
    __syncthreads();

    if (tid < 100) {
        float t = fc1b[tid];
        for (int i = 0; i < 128; i++) t = fmaf(sr[i], fc1w[i * 100 + tid], t);
        sz1[tid] = fmaxf(t, 0.f);
    }
    __syncthreads();
    if (tid < 64) {
        float t = fc2b[tid];
        for (int i = 0; i < 100; i++) t = fmaf(sz1[i], fc2w[i * 64 + tid], t);
        sz2[tid] = fmaxf(t, 0.f);
    }
    __syncthreads();
    if (tid < 64) {
        float p = sz2[tid] * fc3w[tid];
#pragma unroll
        for (int off = 32; off > 0; off >>= 1) p += __shfl_down(p, off, 64);
        if (tid == 0) {
            const float z = p + fc3b[0];
            out[g] = 1.0f / (1.0f + expf(-z));
        }
    }
}

extern "C" void kernel_launch(void* const* d_in, const int* in_sizes, int n_in,
                              void* d_out, int out_size, void* d_ws, size_t ws_size,
                              hipStream_t stream) {
    (void)in_sizes; (void)n_in; (void)out_size; (void)ws_size;
    const float* features = (const float*)d_in[0];
    const int*   src      = (const int*)d_in[1];
    const int*   dst      = (const int*)d_in[2];
    const int*   etype    = (const int*)d_in[3];
    const int*   n2g      = (const int*)d_in[4];
    const float* bases1   = (const float*)d_in[5];
    const float* comp1    = (const float*)d_in[6];
    const float* bias1    = (const float*)d_in[7];
    const float* bases2   = (const float*)d_in[8];
    const float* comp2    = (const float*)d_in[9];
    const float* bias2    = (const float*)d_in[10];
    const float* bases3   = (const float*)d_in[11];
    const float* comp3    = (const float*)d_in[12];
    const float* bias3    = (const float*)d_in[13];
    const float* gate_w   = (const float*)d_in[14];
    const float* gate_b   = (const float*)d_in[15];
    const float* fc1w     = (const float*)d_in[16];
    const float* fc1b     = (const float*)d_in[17];
    const float* fc2w     = (const float*)d_in[18];
    const float* fc2b     = (const float*)d_in[19];
    const float* fc3w     = (const float*)d_in[20];
    const float* fc3b     = (const float*)d_in[21];
    float* out = (float*)d_out;

    char* w = (char*)d_ws;
    auto alloc = [&](size_t bytes) -> char* {
        char* p = w;
        w += (bytes + 255) & ~(size_t)255;
        return p;
    };
    int*    offsets = (int*)alloc((N_NODES + 1) * sizeof(int));
    int*    cursor  = (int*)alloc(N_NODES * sizeof(int));
    int*    edges   = (int*)alloc(N_EDGES * sizeof(int));
    float*  hA      = (float*)alloc((size_t)N_NODES * DIM * sizeof(float));
    float*  hB      = (float*)alloc((size_t)N_NODES * DIM * sizeof(float));
    float*  gate    = (float*)alloc(N_NODES * sizeof(float));
    ushort* Bhi1    = (ushort*)alloc((size_t)KDIM * DIM * sizeof(ushort));
    ushort* Blo1    = (ushort*)alloc((size_t)KDIM * DIM * sizeof(ushort));
    ushort* Bhi2    = (ushort*)alloc((size_t)KDIM * DIM * sizeof(ushort));
    ushort* Blo2    = (ushort*)alloc((size_t)KDIM * DIM * sizeof(ushort));
    ushort* Bhi3    = (ushort*)alloc((size_t)KDIM * DIM * sizeof(ushort));
    ushort* Blo3    = (ushort*)alloc((size_t)KDIM * DIM * sizeof(ushort));

    // weight packing (bf16 hi/lo, MFMA fragment order)
    k_packB<<<(KDIM * DIM) / 256, 256, 0, stream>>>(bases1, Bhi1, Blo1);
    k_packB<<<(KDIM * DIM) / 256, 256, 0, stream>>>(bases2, Bhi2, Blo2);
    k_packB<<<(KDIM * DIM) / 256, 256, 0, stream>>>(bases3, Bhi3, Blo3);

    // CSR by dst (rebuilt every call)
    k_zero_i<<<(N_NODES + 255) / 256, 256, 0, stream>>>(cursor, N_NODES);
    k_count<<<(N_EDGES + 255) / 256, 256, 0, stream>>>(dst, cursor, N_EDGES);
    k_scan<<<1, 1024, 0, stream>>>(cursor, offsets, N_NODES);
    k_fill<<<(N_EDGES + 255) / 256, 256, 0, stream>>>(src, dst, etype, cursor, edges, N_EDGES);

    // 3 RGCN layers (aggregate-first + fused MFMA GEMM)
    k_layer<true><<<N_NODES / NB, 256, 0, stream>>>(features, hA, edges, offsets, comp1, Bhi1, Blo1, bias1);
    k_layer<true><<<N_NODES / NB, 256, 0, stream>>>(hA, hB, edges, offsets, comp2, Bhi2, Blo2, bias2);
    k_layer<false><<<N_NODES / NB, 256, 0, stream>>>(hB, hA, edges, offsets, comp3, Bhi3, Blo3, bias3);

    // attention gate + pooling + MLP head
    k_gate<<<N_NODES / 4, 256, 0, stream>>>(hA, gate_w, gate_b, gate, N_NODES);
    k_pool<<<N_GRAPHS, 128, 0, stream>>>(hA, gate, n2g, fc1w, fc1b, fc2w, fc2b, fc3w, fc3b, out, N_NODES);
}

// Round 5
// 739.975 us; speedup vs baseline: 2.3765x; 1.3526x over previous
//
#include <hip/hip_runtime.h>
#include <hip/hip_bf16.h>
#include <math.h>

#define N_NODES 50000
#define N_EDGES 600000
#define DIM 128
#define N_REL 8
#define N_BASES 8
#define N_GRAPHS 256
#define NB 16                 // nodes per block in layer kernel (50000 = 3125*16 exact)
#define KDIM (N_BASES * DIM)  // 1024
#define SEG 1024
#define NSEG 49               // ceil(50000/1024); NSEG*SEG = 50176

typedef __attribute__((ext_vector_type(8))) short short8;
typedef __attribute__((ext_vector_type(4))) float floatx4;
typedef __attribute__((ext_vector_type(4))) float f32x4;
typedef __attribute__((ext_vector_type(2))) float f32x2;
typedef unsigned int uint;
typedef unsigned short ushort;

static __device__ __forceinline__ int lower_bound_i(const int* a, int n, int v) {
    int lo = 0, hi = n;
    while (lo < hi) { int mid = (lo + hi) >> 1; if (a[mid] < v) lo = mid + 1; else hi = mid; }
    return lo;
}

// RNE float->bf16 split: hiword = bf16(x)|bf16(y)<<16 ; loword = bf16(x-hi)|bf16(y-hi)<<16
static __device__ __forceinline__ uint2 split2(float x, float y) {
    uint ux = __float_as_uint(x);
    uint hx = (ux + 0x7FFFu + ((ux >> 16) & 1u)) & 0xFFFF0000u;
    float rx = x - __uint_as_float(hx);
    uint urx = __float_as_uint(rx);
    uint lx = (urx + 0x7FFFu + ((urx >> 16) & 1u)) >> 16;
    uint uy = __float_as_uint(y);
    uint hy = (uy + 0x7FFFu + ((uy >> 16) & 1u)) & 0xFFFF0000u;
    float ry = y - __uint_as_float(hy);
    uint ury = __float_as_uint(ry);
    uint ly = (ury + 0x7FFFu + ((ury >> 16) & 1u)) >> 16;
    return make_uint2((hx >> 16) | (hy & 0xFFFF0000u), lx | (ly << 16));
}

__global__ void k_zero_i(int* p, int n) {
    int i = blockIdx.x * blockDim.x + threadIdx.x;
    if (i < n) p[i] = 0;
}

__global__ void k_count(const int* __restrict__ dst, int* __restrict__ counts, int e) {
    int i = blockIdx.x * blockDim.x + threadIdx.x;
    if (i < e) atomicAdd(&counts[dst[i]], 1);
}

// --- coalesced 3-kernel exclusive scan over counts[NSEG*SEG] (padding zeroed) ---
__global__ __launch_bounds__(256) void k_scan_seg(const int* __restrict__ counts,
                                                  int* __restrict__ segscan,
                                                  int* __restrict__ segtot) {
    const int b = blockIdx.x, t = threadIdx.x;
    const int base = b * SEG + t * 4;
    const int4 v = *(const int4*)(counts + base);
    const int s0 = v.x, s1 = s0 + v.y, s2 = s1 + v.z, s3 = s2 + v.w;
    __shared__ int sl[256];
    sl[t] = s3;
    __syncthreads();
    for (int off = 1; off < 256; off <<= 1) {
        int add = (t >= off) ? sl[t - off] : 0;
        __syncthreads();
        sl[t] += add;
        __syncthreads();
    }
    const int tp = sl[t] - s3;  // exclusive prefix of this thread within segment
    int4 o;
    o.x = tp; o.y = tp + s0; o.z = tp + s1; o.w = tp + s2;
    *(int4*)(segscan + base) = o;
    if (t == 255) segtot[b] = sl[255];
}

__global__ void k_scan_tot(const int* __restrict__ segtot, int* __restrict__ segbase) {
    const int t = threadIdx.x;  // 64 threads, 1 block
    const int v = (t < NSEG) ? segtot[t] : 0;
    int s = v;
#pragma unroll
    for (int off = 1; off < 64; off <<= 1) {
        int u = __shfl_up(s, off, 64);
        if (t >= off) s += u;
    }
    if (t <= NSEG) segbase[t] = s - v;  // exclusive; segbase[NSEG] = total
}

__global__ void k_scan_fin(const int* __restrict__ segscan, const int* __restrict__ segbase,
                           int* __restrict__ offsets, int* __restrict__ cursor) {
    const int i = blockIdx.x * blockDim.x + threadIdx.x;
    if (i < N_NODES) {
        const int val = segbase[i >> 10] + segscan[i];
        offsets[i] = val;
        cursor[i] = val;
    } else if (i == N_NODES) {
        offsets[N_NODES] = segbase[NSEG];
    }
}

__global__ void k_fill(const int* __restrict__ src, const int* __restrict__ dst,
                       const int* __restrict__ etype, int* cursor,
                       int* __restrict__ edges, int e) {
    int i = blockIdx.x * blockDim.x + threadIdx.x;
    if (i < e) {
        int d = dst[i];
        int pos = atomicAdd(&cursor[d], 1);
        edges[pos] = src[i] | (etype[i] << 16);
    }
}

// Pack bases [K=1024][N=128] fp32 into MFMA-B-fragment-ordered bf16 hi/lo:
// layout [kt:32][n:128][kk:32] ushort. Thread mapping chosen for coalesced WRITES.
__global__ void k_packB(const float* __restrict__ bases, ushort* __restrict__ Bhi,
                        ushort* __restrict__ Blo) {
    int id = blockIdx.x * blockDim.x + threadIdx.x;  // 131072
    int kk = id & 31, nn = (id >> 5) & 127, kt = id >> 12;
    int k = kt * 32 + kk;
    float v = bases[(size_t)k * DIM + nn];
    uint u = __float_as_uint(v);
    uint hu = (u + 0x7FFFu + ((u >> 16) & 1u)) & 0xFFFF0000u;
    float rf = v - __uint_as_float(hu);
    uint ur = __float_as_uint(rf);
    uint lu = (ur + 0x7FFFu + ((ur >> 16) & 1u)) >> 16;
    int off = kt * 4096 + nn * 32 + kk;  // == id -> coalesced
    Bhi[off] = (ushort)(hu >> 16);
    Blo[off] = (ushort)lu;
}

// One RGCN layer, fused:
//  phase 1: aggregate incoming edges into basis space. 2 nodes per wave in
//           parallel (half-wave each, 4 dims/lane = 16B gathers), descriptor
//           prefetch pipeline, comp in LDS. Write bf16 hi/lo to MFMA-packed
//           LDS with kt-parity XOR swizzle (spreads writes over 32 banks).
//  phase 2: [16 x 1024] @ [1024 x 128] via mfma_f32_16x16x32_bf16, 3-term split.
//
// PITFALL (R3): do NOT scalarize loads of per-call-rebuilt arrays
// (edges/offsets/segscan/...). Provably wave-uniform addresses let the
// compiler use s_load through the scalar cache, which serves STALE lines from
// the previous call's array contents -> wrong output on graph replay. Keep
// lane-derived (vector) addressing for all such loads. [R2/R4 passed, R3
// failed the replay tripwire with exactly this delta.]
template <bool RELU>
__global__ __launch_bounds__(256, 2) void k_layer(
    const float* __restrict__ xin, float* __restrict__ hout,
    const int* __restrict__ edges, const int* __restrict__ offsets,
    const float* __restrict__ comp,
    const ushort* __restrict__ Bhi, const ushort* __restrict__ Blo,
    const float* __restrict__ bias) {
    __shared__ ushort sHi[NB * KDIM];  // 32 KiB
    __shared__ ushort sLo[NB * KDIM];  // 32 KiB
    __shared__ float scomp[N_REL * 8];
    const int tid = threadIdx.x;
    const int w = tid >> 6;
    const int lane = tid & 63;
    if (tid < 64) scomp[tid] = comp[tid];
    __syncthreads();

    // ---- phase 1: edge aggregation; half-wave per node, 4 dims/lane ----
    {
        const int half = lane >> 5;
        const int l5 = lane & 31;
        const int d0 = l5 * 4;           // this lane's 4 dims
        const int kt_off = d0 >> 5;      // 0..3 (sub-tile within each basis b)
        const int q = (d0 >> 3) & 3;
        const int jb = d0 & 7;           // 0 or 4
        for (int p = 0; p < 2; ++p) {
            const int nl = p * 8 + w * 2 + half;
            const int n = blockIdx.x * NB + nl;
            f32x4 acc[N_BASES];
#pragma unroll
            for (int b = 0; b < N_BASES; b++) acc[b] = (f32x4)0.f;
            const int e0 = offsets[n], e1 = offsets[n + 1];
            int e = e0;
            const int nb4 = (e1 - e0) >> 2;
            if (nb4 > 0) {
                int pc0 = edges[e], pc1 = edges[e + 1], pc2 = edges[e + 2], pc3 = edges[e + 3];
                for (int it = 0; it < nb4; ++it) {
                    // issue gathers for current batch (4 in flight per half-wave)
                    const f32x4 v0 = *(const f32x4*)(xin + (size_t)(pc0 & 0xFFFF) * DIM + d0);
                    const f32x4 v1 = *(const f32x4*)(xin + (size_t)(pc1 & 0xFFFF) * DIM + d0);
                    const f32x4 v2 = *(const f32x4*)(xin + (size_t)(pc2 & 0xFFFF) * DIM + d0);
                    const f32x4 v3 = *(const f32x4*)(xin + (size_t)(pc3 & 0xFFFF) * DIM + d0);
                    // prefetch next batch's descriptors (overlaps with FMAs below)
                    int pn0, pn1, pn2, pn3;
                    const int en = e + 4;
                    if (it + 1 < nb4) {
                        pn0 = edges[en]; pn1 = edges[en + 1]; pn2 = edges[en + 2]; pn3 = edges[en + 3];
                    } else {
                        pn0 = pn1 = pn2 = pn3 = 0;
                    }
                    // comp rows from LDS (no global dependency in the chain)
                    const float4 ca0 = *(const float4*)&scomp[(pc0 >> 16) * 8];
                    const float4 cb0 = *(const float4*)&scomp[(pc0 >> 16) * 8 + 4];
                    const float4 ca1 = *(const float4*)&scomp[(pc1 >> 16) * 8];
                    const float4 cb1 = *(const float4*)&scomp[(pc1 >> 16) * 8 + 4];
                    const float4 ca2 = *(const float4*)&scomp[(pc2 >> 16) * 8];
                    const float4 cb2 = *(const float4*)&scomp[(pc2 >> 16) * 8 + 4];
                    const float4 ca3 = *(const float4*)&scomp[(pc3 >> 16) * 8];
                    const float4 cb3 = *(const float4*)&scomp[(pc3 >> 16) * 8 + 4];
                    const float cw0[8] = {ca0.x, ca0.y, ca0.z, ca0.w, cb0.x, cb0.y, cb0.z, cb0.w};
                    const float cw1[8] = {ca1.x, ca1.y, ca1.z, ca1.w, cb1.x, cb1.y, cb1.z, cb1.w};
                    const float cw2[8] = {ca2.x, ca2.y, ca2.z, ca2.w, cb2.x, cb2.y, cb2.z, cb2.w};
                    const float cw3[8] = {ca3.x, ca3.y, ca3.z, ca3.w, cb3.x, cb3.y, cb3.z, cb3.w};
#pragma unroll
                    for (int b = 0; b < 8; b++) {
                        acc[b] = __builtin_elementwise_fma((f32x4)cw0[b], v0, acc[b]);
                        acc[b] = __builtin_elementwise_fma((f32x4)cw1[b], v1, acc[b]);
                        acc[b] = __builtin_elementwise_fma((f32x4)cw2[b], v2, acc[b]);
                        acc[b] = __builtin_elementwise_fma((f32x4)cw3[b], v3, acc[b]);
                    }
                    e = en;
                    pc0 = pn0; pc1 = pn1; pc2 = pn2; pc3 = pn3;
                }
            }
            for (; e < e1; ++e) {  // tail 0..3 edges
                const int pk = edges[e];
                const f32x4 v = *(const f32x4*)(xin + (size_t)(pk & 0xFFFF) * DIM + d0);
                const float4 ca = *(const float4*)&scomp[(pk >> 16) * 8];
                const float4 cb = *(const float4*)&scomp[(pk >> 16) * 8 + 4];
                const float cw[8] = {ca.x, ca.y, ca.z, ca.w, cb.x, cb.y, cb.z, cb.w};
#pragma unroll
                for (int b = 0; b < 8; b++) acc[b] = __builtin_elementwise_fma((f32x4)cw[b], v, acc[b]);
            }
            // write 4 bf16 hi + 4 bf16 lo per basis to swizzled LDS
#pragma unroll
            for (int b = 0; b < 8; b++) {
                const int kt = b * 4 + kt_off;
                const int chunk = q * 16 + ((nl ^ q) ^ ((kt & 1) << 2));
                const int uoff = kt * 512 + chunk * 8 + jb;  // ushort offset, 8B aligned
                const uint2 p01 = split2(acc[b].x, acc[b].y);
                const uint2 p23 = split2(acc[b].z, acc[b].w);
                *(uint2*)(sHi + uoff) = make_uint2(p01.x, p23.x);
                *(uint2*)(sLo + uoff) = make_uint2(p01.y, p23.y);
            }
        }
    }
    __syncthreads();

    // ---- phase 2: MFMA GEMM, wave owns 32-col strip (two 16-wide n-tiles) ----
    const int q2 = lane >> 4, mm = lane & 15;
    const int a_even = (q2 * 16 + (mm ^ q2)) * 8;        // kt even
    const int a_odd  = (q2 * 16 + ((mm ^ q2) ^ 4)) * 8;  // kt odd (parity swizzle)
    const int n0 = w * 32 + mm, n1 = n0 + 16;
    floatx4 acc0 = {0.f, 0.f, 0.f, 0.f};
    floatx4 acc1 = {0.f, 0.f, 0.f, 0.f};
    for (int kt = 0; kt < 32; kt += 2) {
        {
            const short8 ah = *(const short8*)(sHi + kt * 512 + a_even);
            const short8 al = *(const short8*)(sLo + kt * 512 + a_even);
            const short8 bh0 = *(const short8*)(Bhi + kt * 4096 + n0 * 32 + q2 * 8);
            const short8 bl0 = *(const short8*)(Blo + kt * 4096 + n0 * 32 + q2 * 8);
            const short8 bh1 = *(const short8*)(Bhi + kt * 4096 + n1 * 32 + q2 * 8);
            const short8 bl1 = *(const short8*)(Blo + kt * 4096 + n1 * 32 + q2 * 8);
            acc0 = __builtin_amdgcn_mfma_f32_16x16x32_bf16(ah, bh0, acc0, 0, 0, 0);
            acc1 = __builtin_amdgcn_mfma_f32_16x16x32_bf16(ah, bh1, acc1, 0, 0, 0);
            acc0 = __builtin_amdgcn_mfma_f32_16x16x32_bf16(ah, bl0, acc0, 0, 0, 0);
            acc1 = __builtin_amdgcn_mfma_f32_16x16x32_bf16(ah, bl1, acc1, 0, 0, 0);
            acc0 = __builtin_amdgcn_mfma_f32_16x16x32_bf16(al, bh0, acc0, 0, 0, 0);
            acc1 = __builtin_amdgcn_mfma_f32_16x16x32_bf16(al, bh1, acc1, 0, 0, 0);
        }
        {
            const int kto = kt + 1;
            const short8 ah = *(const short8*)(sHi + kto * 512 + a_odd);
            const short8 al = *(const short8*)(sLo + kto * 512 + a_odd);
            const short8 bh0 = *(const short8*)(Bhi + kto * 4096 + n0 * 32 + q2 * 8);
            const short8 bl0 = *(const short8*)(Blo + kto * 4096 + n0 * 32 + q2 * 8);
            const short8 bh1 = *(const short8*)(Bhi + kto * 4096 + n1 * 32 + q2 * 8);
            const short8 bl1 = *(const short8*)(Blo + kto * 4096 + n1 * 32 + q2 * 8);
            acc0 = __builtin_amdgcn_mfma_f32_16x16x32_bf16(ah, bh0, acc0, 0, 0, 0);
            acc1 = __builtin_amdgcn_mfma_f32_16x16x32_bf16(ah, bh1, acc1, 0, 0, 0);
            acc0 = __builtin_amdgcn_mfma_f32_16x16x32_bf16(ah, bl0, acc0, 0, 0, 0);
            acc1 = __builtin_amdgcn_mfma_f32_16x16x32_bf16(ah, bl1, acc1, 0, 0, 0);
            acc0 = __builtin_amdgcn_mfma_f32_16x16x32_bf16(al, bh0, acc0, 0, 0, 0);
            acc1 = __builtin_amdgcn_mfma_f32_16x16x32_bf16(al, bh1, acc1, 0, 0, 0);
        }
    }
    const float b0 = bias[n0], b1 = bias[n1];
#pragma unroll
    for (int r = 0; r < 4; r++) {
        const int node = blockIdx.x * NB + q2 * 4 + r;  // C/D: row=(lane>>4)*4+reg, col=lane&15
        float v0 = acc0[r] + b0;
        float v1 = acc1[r] + b1;
        if (RELU) { v0 = fmaxf(v0, 0.f); v1 = fmaxf(v1, 0.f); }
        hout[(size_t)node * DIM + n0] = v0;
        hout[(size_t)node * DIM + n1] = v1;
    }
}

// gate[n] = dot(h3[n,:], gate_w) + gate_b  (one wave per node)
__global__ void k_gate(const float* __restrict__ h3, const float* __restrict__ gw,
                       const float* __restrict__ gb, float* __restrict__ gate, int N) {
    const int n = blockIdx.x * 4 + (threadIdx.x >> 6);
    const int lane = threadIdx.x & 63;
    if (n >= N) return;
    const float2 v = *(const float2*)(h3 + (size_t)n * DIM + lane * 2);
    const float2 g = *(const float2*)(gw + lane * 2);
    float p = v.x * g.x + v.y * g.y;
#pragma unroll
    for (int off = 32; off > 0; off >>= 1) p += __shfl_down(p, off, 64);
    if (lane == 0) gate[n] = p + gb[0];
}

// One block (128 threads) per graph: segment softmax + weighted readout + MLP head + sigmoid.
__global__ __launch_bounds__(128) void k_pool(
    const float* __restrict__ h3, const float* __restrict__ gate, const int* __restrict__ n2g,
    const float* __restrict__ fc1w, const float* __restrict__ fc1b,
    const float* __restrict__ fc2w, const float* __restrict__ fc2b,
    const float* __restrict__ fc3w, const float* __restrict__ fc3b,
    float* __restrict__ out, int N) {
    const int g = blockIdx.x;
    const int tid = threadIdx.x;
    __shared__ float sred[128];
    __shared__ float sr[128];
    __shared__ float sz1[100];
    __shared__ float sz2[64];
    __shared__ float sm, ssum;

    const int s = lower_bound_i(n2g, N, g);
    const int e = lower_bound_i(n2g, N, g + 1);

    float m = -3.4e38f;
    for (int n = s + tid; n < e; n += 128) m = fmaxf(m, gate[n]);
    sred[tid] = m;
    __syncthreads();
    for (int off = 64; off > 0; off >>= 1) {
        if (tid < off) sred[tid] = fmaxf(sred[tid], sred[tid + off]);
        __syncthreads();
    }
    if (tid == 0) sm = sred[0];
    __syncthreads();
    const float mm = sm;

    float sum = 0.f;
    for (int n = s + tid; n < e; n += 128) sum += expf(gate[n] - mm);
    sred[tid] = sum;
    __syncthreads();
    for (int off = 64; off > 0; off >>= 1) {
        if (tid < off) sred[tid] += sred[tid + off];
        __syncthreads();
    }
    if (tid == 0) ssum = sred[0];
    __syncthreads();
    const float inv = (e > s) ? 1.0f / ssum : 0.f;

    // weighted readout, thread owns dim o = tid; node loop unrolled x4
    float acc = 0.f;
    int n = s;
    for (; n + 4 <= e; n += 4) {
        const float w0 = expf(gate[n + 0] - mm);
        const float w1 = expf(gate[n + 1] - mm);
        const float w2 = expf(gate[n + 2] - mm);
        const float w3 = expf(gate[n + 3] - mm);
        const float a0 = h3[(size_t)(n + 0) * DIM + tid];
        const float a1 = h3[(size_t)(n + 1) * DIM + tid];
        const float a2 = h3[(size_t)(n + 2) * DIM + tid];
        const float a3 = h3[(size_t)(n + 3) * DIM + tid];
        acc = fmaf(w0, a0, acc);
        acc = fmaf(w1, a1, acc);
        acc = fmaf(w2, a2, acc);
        acc = fmaf(w3, a3, acc);
    }
    for (; n < e; ++n) {
        const float wgt = expf(gate[n] - mm);
        acc = fmaf(wgt, h3[(size_t)n * DIM + tid], acc);
    }
    sr[tid] = acc * inv;
    __syncthreads();

    if (tid < 100) {
        float t = fc1b[tid];
        for (int i = 0; i < 128; i++) t = fmaf(sr[i], fc1w[i * 100 + tid], t);
        sz1[tid] = fmaxf(t, 0.f);
    }
    __syncthreads();
    if (tid < 64) {
        float t = fc2b[tid];
        for (int i = 0; i < 100; i++) t = fmaf(sz1[i], fc2w[i * 64 + tid], t);
        sz2[tid] = fmaxf(t, 0.f);
    }
    __syncthreads();
    if (tid < 64) {
        float p = sz2[tid] * fc3w[tid];
#pragma unroll
        for (int off = 32; off > 0; off >>= 1) p += __shfl_down(p, off, 64);
        if (tid == 0) {
            const float z = p + fc3b[0];
            out[g] = 1.0f / (1.0f + expf(-z));
        }
    }
}

extern "C" void kernel_launch(void* const* d_in, const int* in_sizes, int n_in,
                              void* d_out, int out_size, void* d_ws, size_t ws_size,
                              hipStream_t stream) {
    (void)in_sizes; (void)n_in; (void)out_size; (void)ws_size;
    const float* features = (const float*)d_in[0];
    const int*   src      = (const int*)d_in[1];
    const int*   dst      = (const int*)d_in[2];
    const int*   etype    = (const int*)d_in[3];
    const int*   n2g      = (const int*)d_in[4];
    const float* bases1   = (const float*)d_in[5];
    const float* comp1    = (const float*)d_in[6];
    const float* bias1    = (const float*)d_in[7];
    const float* bases2   = (const float*)d_in[8];
    const float* comp2    = (const float*)d_in[9];
    const float* bias2    = (const float*)d_in[10];
    const float* bases3   = (const float*)d_in[11];
    const float* comp3    = (const float*)d_in[12];
    const float* bias3    = (const float*)d_in[13];
    const float* gate_w   = (const float*)d_in[14];
    const float* gate_b   = (const float*)d_in[15];
    const float* fc1w     = (const float*)d_in[16];
    const float* fc1b     = (const float*)d_in[17];
    const float* fc2w     = (const float*)d_in[18];
    const float* fc2b     = (const float*)d_in[19];
    const float* fc3w     = (const float*)d_in[20];
    const float* fc3b     = (const float*)d_in[21];
    float* out = (float*)d_out;

    char* w = (char*)d_ws;
    auto alloc = [&](size_t bytes) -> char* {
        char* p = w;
        w += (bytes + 255) & ~(size_t)255;
        return p;
    };
    int*    offsets = (int*)alloc((N_NODES + 1) * sizeof(int));
    int*    cursor  = (int*)alloc((size_t)NSEG * SEG * sizeof(int));  // counts (padded), then fill cursor
    int*    edges   = (int*)alloc(N_EDGES * sizeof(int));
    int*    segscan = (int*)alloc((size_t)NSEG * SEG * sizeof(int));
    int*    segtot  = (int*)alloc(64 * sizeof(int));
    int*    segbase = (int*)alloc(64 * sizeof(int));
    float*  hA      = (float*)alloc((size_t)N_NODES * DIM * sizeof(float));
    float*  hB      = (float*)alloc((size_t)N_NODES * DIM * sizeof(float));
    float*  gate    = (float*)alloc(N_NODES * sizeof(float));
    ushort* Bhi1    = (ushort*)alloc((size_t)KDIM * DIM * sizeof(ushort));
    ushort* Blo1    = (ushort*)alloc((size_t)KDIM * DIM * sizeof(ushort));
    ushort* Bhi2    = (ushort*)alloc((size_t)KDIM * DIM * sizeof(ushort));
    ushort* Blo2    = (ushort*)alloc((size_t)KDIM * DIM * sizeof(ushort));
    ushort* Bhi3    = (ushort*)alloc((size_t)KDIM * DIM * sizeof(ushort));
    ushort* Blo3    = (ushort*)alloc((size_t)KDIM * DIM * sizeof(ushort));

    // weight packing (bf16 hi/lo, MFMA fragment order)
    k_packB<<<(KDIM * DIM) / 256, 256, 0, stream>>>(bases1, Bhi1, Blo1);
    k_packB<<<(KDIM * DIM) / 256, 256, 0, stream>>>(bases2, Bhi2, Blo2);
    k_packB<<<(KDIM * DIM) / 256, 256, 0, stream>>>(bases3, Bhi3, Blo3);

    // CSR by dst (rebuilt every call)
    k_zero_i<<<(NSEG * SEG + 255) / 256, 256, 0, stream>>>(cursor, NSEG * SEG);
    k_count<<<(N_EDGES + 255) / 256, 256, 0, stream>>>(dst, cursor, N_EDGES);
    k_scan_seg<<<NSEG, 256, 0, stream>>>(cursor, segscan, segtot);
    k_scan_tot<<<1, 64, 0, stream>>>(segtot, segbase);
    k_scan_fin<<<(N_NODES + 256) / 256, 256, 0, stream>>>(segscan, segbase, offsets, cursor);
    k_fill<<<(N_EDGES + 255) / 256, 256, 0, stream>>>(src, dst, etype, cursor, edges, N_EDGES);

    // 3 RGCN layers (aggregate-first + fused MFMA GEMM)
    k_layer<true><<<N_NODES / NB, 256, 0, stream>>>(features, hA, edges, offsets, comp1, Bhi1, Blo1, bias1);
    k_layer<true><<<N_NODES / NB, 256, 0, stream>>>(hA, hB, edges, offsets, comp2, Bhi2, Blo2, bias2);
    k_layer<false><<<N_NODES / NB, 256, 0, stream>>>(hB, hA, edges, offsets, comp3, Bhi3, Blo3, bias3);

    // attention gate + pooling + MLP head
    k_gate<<<N_NODES / 4, 256, 0, stream>>>(hA, gate_w, gate_b, gate, N_NODES);
    k_pool<<<N_GRAPHS, 128, 0, stream>>>(hA, gate, n2g, fc1w, fc1b, fc2w, fc2b, fc3w, fc3b, out, N_NODES);
}

// Round 6
// 621.876 us; speedup vs baseline: 2.8278x; 1.1899x over previous
//
#include <hip/hip_runtime.h>
#include <hip/hip_bf16.h>
#include <math.h>

#define N_NODES 50000
#define N_EDGES 600000
#define DIM 128
#define N_REL 8
#define N_BASES 8
#define N_GRAPHS 256
#define NB 16                 // nodes per block in layer kernel (50000 = 3125*16 exact)
#define KDIM (N_BASES * DIM)  // 1024
#define SEG 1024
#define NSEG 49               // ceil(50000/1024); NSEG*SEG = 50176

typedef __attribute__((ext_vector_type(8))) short short8;
typedef __attribute__((ext_vector_type(4))) float floatx4;
typedef __attribute__((ext_vector_type(4))) float f32x4;
typedef unsigned int uint;
typedef unsigned short ushort;

static __device__ __forceinline__ int lower_bound_i(const int* a, int n, int v) {
    int lo = 0, hi = n;
    while (lo < hi) { int mid = (lo + hi) >> 1; if (a[mid] < v) lo = mid + 1; else hi = mid; }
    return lo;
}

// RNE float->bf16 split: hiword = bf16(x)|bf16(y)<<16 ; loword = bf16(x-hi)|bf16(y-hi)<<16
static __device__ __forceinline__ uint2 split2(float x, float y) {
    uint ux = __float_as_uint(x);
    uint hx = (ux + 0x7FFFu + ((ux >> 16) & 1u)) & 0xFFFF0000u;
    float rx = x - __uint_as_float(hx);
    uint urx = __float_as_uint(rx);
    uint lx = (urx + 0x7FFFu + ((urx >> 16) & 1u)) >> 16;
    uint uy = __float_as_uint(y);
    uint hy = (uy + 0x7FFFu + ((uy >> 16) & 1u)) & 0xFFFF0000u;
    float ry = y - __uint_as_float(hy);
    uint ury = __float_as_uint(ry);
    uint ly = (ury + 0x7FFFu + ((ury >> 16) & 1u)) >> 16;
    return make_uint2((hx >> 16) | (hy & 0xFFFF0000u), lx | (ly << 16));
}

__global__ void k_count(const int* __restrict__ dst, int* __restrict__ counts, int e) {
    int i = blockIdx.x * blockDim.x + threadIdx.x;
    if (i < e) atomicAdd(&counts[dst[i]], 1);
}

// --- coalesced 3-kernel exclusive scan over counts[NSEG*SEG] (padding zeroed) ---
__global__ __launch_bounds__(256) void k_scan_seg(const int* __restrict__ counts,
                                                  int* __restrict__ segscan,
                                                  int* __restrict__ segtot) {
    const int b = blockIdx.x, t = threadIdx.x;
    const int base = b * SEG + t * 4;
    const int4 v = *(const int4*)(counts + base);
    const int s0 = v.x, s1 = s0 + v.y, s2 = s1 + v.z, s3 = s2 + v.w;
    __shared__ int sl[256];
    sl[t] = s3;
    __syncthreads();
    for (int off = 1; off < 256; off <<= 1) {
        int add = (t >= off) ? sl[t - off] : 0;
        __syncthreads();
        sl[t] += add;
        __syncthreads();
    }
    const int tp = sl[t] - s3;  // exclusive prefix of this thread within segment
    int4 o;
    o.x = tp; o.y = tp + s0; o.z = tp + s1; o.w = tp + s2;
    *(int4*)(segscan + base) = o;
    if (t == 255) segtot[b] = sl[255];
}

__global__ void k_scan_tot(const int* __restrict__ segtot, int* __restrict__ segbase) {
    const int t = threadIdx.x;  // 64 threads, 1 block
    const int v = (t < NSEG) ? segtot[t] : 0;
    int s = v;
#pragma unroll
    for (int off = 1; off < 64; off <<= 1) {
        int u = __shfl_up(s, off, 64);
        if (t >= off) s += u;
    }
    if (t <= NSEG) segbase[t] = s - v;  // exclusive; segbase[NSEG] = total
}

__global__ void k_scan_fin(const int* __restrict__ segscan, const int* __restrict__ segbase,
                           int* __restrict__ offsets, int* __restrict__ cursor) {
    const int i = blockIdx.x * blockDim.x + threadIdx.x;
    if (i < N_NODES) {
        const int val = segbase[i >> 10] + segscan[i];
        offsets[i] = val;
        cursor[i] = val;
    } else if (i == N_NODES) {
        offsets[N_NODES] = segbase[NSEG];
    }
}

__global__ void k_fill(const int* __restrict__ src, const int* __restrict__ dst,
                       const int* __restrict__ etype, int* cursor,
                       int* __restrict__ edges, int e) {
    int i = blockIdx.x * blockDim.x + threadIdx.x;
    if (i < e) {
        int d = dst[i];
        int pos = atomicAdd(&cursor[d], 1);
        edges[pos] = src[i] | (etype[i] << 16);
    }
}

// Pack bases [K=1024][N=128] fp32 into MFMA-B-fragment-ordered bf16 hi/lo:
// layout [kt:32][n:128][kk:32] ushort. Thread mapping chosen for coalesced WRITES.
__global__ void k_packB(const float* __restrict__ bases, ushort* __restrict__ Bhi,
                        ushort* __restrict__ Blo) {
    int id = blockIdx.x * blockDim.x + threadIdx.x;  // 131072
    int kk = id & 31, nn = (id >> 5) & 127, kt = id >> 12;
    int k = kt * 32 + kk;
    float v = bases[(size_t)k * DIM + nn];
    uint u = __float_as_uint(v);
    uint hu = (u + 0x7FFFu + ((u >> 16) & 1u)) & 0xFFFF0000u;
    float rf = v - __uint_as_float(hu);
    uint ur = __float_as_uint(rf);
    uint lu = (ur + 0x7FFFu + ((ur >> 16) & 1u)) >> 16;
    int off = kt * 4096 + nn * 32 + kk;  // == id -> coalesced
    Bhi[off] = (ushort)(hu >> 16);
    Blo[off] = (ushort)lu;
}

// One RGCN layer, fused, 512 threads (8 waves):
//  phase 1: one node per HALF-WAVE (16 half-waves = all NB nodes in parallel),
//           4 dims/lane (16B gathers), 2-stage pipeline: descriptors prefetched
//           2 batches ahead, gathers issued 1 batch ahead (issue order
//           desc(i+2) -> gathers(i+1) -> FMA(i) keeps ~8 loads in flight).
//           comp in LDS. bf16 hi/lo written to MFMA-packed swizzled LDS.
//  phase 2: wave owns one 16-col strip; [16 x 1024] @ [1024 x 128] via
//           mfma_f32_16x16x32_bf16, 3-term split (fp32-class accuracy).
//
// PITFALL (R3): do NOT scalarize loads of per-call-rebuilt arrays
// (edges/offsets/...). Provably wave-uniform addresses let the compiler use
// s_load through the scalar cache, which serves STALE lines from the previous
// call's contents -> wrong output on graph replay. Keep lane-derived (vector)
// addressing for all such loads. [R2/R4/R5 passed; R3 failed exactly on this.]
template <bool RELU>
__global__ __launch_bounds__(512, 4) void k_layer(
    const float* __restrict__ xin, float* __restrict__ hout,
    const int* __restrict__ edges, const int* __restrict__ offsets,
    const float* __restrict__ comp,
    const ushort* __restrict__ Bhi, const ushort* __restrict__ Blo,
    const float* __restrict__ bias) {
    __shared__ ushort sHi[NB * KDIM];  // 32 KiB
    __shared__ ushort sLo[NB * KDIM];  // 32 KiB
    __shared__ float scomp[N_REL * 8];
    const int tid = threadIdx.x;
    if (tid < 64) scomp[tid] = comp[tid];
    __syncthreads();

    // ---- phase 1: edge aggregation; one node per half-wave, 4 dims/lane ----
    {
        const int nl = tid >> 5;         // 0..15 — this half-wave's node
        const int l5 = tid & 31;
        const int d0 = l5 * 4;           // this lane's 4 dims
        const int kt_off = l5 >> 3;      // 0..3
        const int q = (l5 >> 1) & 3;
        const int jb = (l5 & 1) * 4;
        const int n = blockIdx.x * NB + nl;
        f32x4 acc[N_BASES];
#pragma unroll
        for (int b = 0; b < N_BASES; b++) acc[b] = (f32x4)0.f;
        const int e0 = offsets[n], e1 = offsets[n + 1];
        const int nb4 = (e1 - e0) >> 2;
        int e = e0;
        if (nb4 > 0) {
            // prologue: batch-0 descriptors + gathers; batch-1 descriptors
            int pc0 = edges[e], pc1 = edges[e + 1], pc2 = edges[e + 2], pc3 = edges[e + 3];
            f32x4 vc0 = *(const f32x4*)(xin + (size_t)(pc0 & 0xFFFF) * DIM + d0);
            f32x4 vc1 = *(const f32x4*)(xin + (size_t)(pc1 & 0xFFFF) * DIM + d0);
            f32x4 vc2 = *(const f32x4*)(xin + (size_t)(pc2 & 0xFFFF) * DIM + d0);
            f32x4 vc3 = *(const f32x4*)(xin + (size_t)(pc3 & 0xFFFF) * DIM + d0);
            int pn0 = 0, pn1 = 0, pn2 = 0, pn3 = 0;
            if (nb4 > 1) {
                pn0 = edges[e + 4]; pn1 = edges[e + 5]; pn2 = edges[e + 6]; pn3 = edges[e + 7];
            }
            for (int it = 0; it < nb4; ++it) {
                // 1) descriptors for batch it+2 (issued FIRST so waiting on pn
                //    later never drains the in-flight gathers)
                int pf0, pf1, pf2, pf3;
                if (it + 2 < nb4) {
                    pf0 = edges[e + 8]; pf1 = edges[e + 9]; pf2 = edges[e + 10]; pf3 = edges[e + 11];
                } else {
                    pf0 = pf1 = pf2 = pf3 = 0;
                }
                // 2) gathers for batch it+1 (descriptors loaded last iteration)
                f32x4 vn0, vn1, vn2, vn3;
                if (it + 1 < nb4) {
                    vn0 = *(const f32x4*)(xin + (size_t)(pn0 & 0xFFFF) * DIM + d0);
                    vn1 = *(const f32x4*)(xin + (size_t)(pn1 & 0xFFFF) * DIM + d0);
                    vn2 = *(const f32x4*)(xin + (size_t)(pn2 & 0xFFFF) * DIM + d0);
                    vn3 = *(const f32x4*)(xin + (size_t)(pn3 & 0xFFFF) * DIM + d0);
                }
                // 3) FMA batch it (gathers issued one iteration ago)
                const float4 ca0 = *(const float4*)&scomp[(pc0 >> 16) * 8];
                const float4 cb0 = *(const float4*)&scomp[(pc0 >> 16) * 8 + 4];
                const float4 ca1 = *(const float4*)&scomp[(pc1 >> 16) * 8];
                const float4 cb1 = *(const float4*)&scomp[(pc1 >> 16) * 8 + 4];
                const float4 ca2 = *(const float4*)&scomp[(pc2 >> 16) * 8];
                const float4 cb2 = *(const float4*)&scomp[(pc2 >> 16) * 8 + 4];
                const float4 ca3 = *(const float4*)&scomp[(pc3 >> 16) * 8];
                const float4 cb3 = *(const float4*)&scomp[(pc3 >> 16) * 8 + 4];
                const float cw0[8] = {ca0.x, ca0.y, ca0.z, ca0.w, cb0.x, cb0.y, cb0.z, cb0.w};
                const float cw1[8] = {ca1.x, ca1.y, ca1.z, ca1.w, cb1.x, cb1.y, cb1.z, cb1.w};
                const float cw2[8] = {ca2.x, ca2.y, ca2.z, ca2.w, cb2.x, cb2.y, cb2.z, cb2.w};
                const float cw3[8] = {ca3.x, ca3.y, ca3.z, ca3.w, cb3.x, cb3.y, cb3.z, cb3.w};
#pragma unroll
                for (int b = 0; b < 8; b++) {
                    acc[b] = __builtin_elementwise_fma((f32x4)cw0[b], vc0, acc[b]);
                    acc[b] = __builtin_elementwise_fma((f32x4)cw1[b], vc1, acc[b]);
                    acc[b] = __builtin_elementwise_fma((f32x4)cw2[b], vc2, acc[b]);
                    acc[b] = __builtin_elementwise_fma((f32x4)cw3[b], vc3, acc[b]);
                }
                // rotate
                pc0 = pn0; pc1 = pn1; pc2 = pn2; pc3 = pn3;
                pn0 = pf0; pn1 = pf1; pn2 = pf2; pn3 = pf3;
                vc0 = vn0; vc1 = vn1; vc2 = vn2; vc3 = vn3;
                e += 4;
            }
        }
        for (; e < e1; ++e) {  // tail 0..3 edges
            const int pk = edges[e];
            const f32x4 v = *(const f32x4*)(xin + (size_t)(pk & 0xFFFF) * DIM + d0);
            const float4 ca = *(const float4*)&scomp[(pk >> 16) * 8];
            const float4 cb = *(const float4*)&scomp[(pk >> 16) * 8 + 4];
            const float cw[8] = {ca.x, ca.y, ca.z, ca.w, cb.x, cb.y, cb.z, cb.w};
#pragma unroll
            for (int b = 0; b < 8; b++) acc[b] = __builtin_elementwise_fma((f32x4)cw[b], v, acc[b]);
        }
        // write 4 bf16 hi + 4 bf16 lo per basis to swizzled LDS
#pragma unroll
        for (int b = 0; b < 8; b++) {
            const int kt = b * 4 + kt_off;
            const int chunk = q * 16 + ((nl ^ q) ^ ((kt & 1) << 2));
            const int uoff = kt * 512 + chunk * 8 + jb;  // ushort offset, 8B aligned
            const uint2 p01 = split2(acc[b].x, acc[b].y);
            const uint2 p23 = split2(acc[b].z, acc[b].w);
            *(uint2*)(sHi + uoff) = make_uint2(p01.x, p23.x);
            *(uint2*)(sLo + uoff) = make_uint2(p01.y, p23.y);
        }
    }
    __syncthreads();

    // ---- phase 2: MFMA GEMM, each of 8 waves owns one 16-col strip ----
    const int w = tid >> 6;
    const int lane = tid & 63;
    const int q2 = lane >> 4, mm = lane & 15;
    const int a_even = (q2 * 16 + (mm ^ q2)) * 8;        // kt even
    const int a_odd  = (q2 * 16 + ((mm ^ q2) ^ 4)) * 8;  // kt odd (parity swizzle)
    const int n0 = w * 16 + mm;
    const ushort* bph = Bhi + n0 * 32 + q2 * 8;
    const ushort* bpl = Blo + n0 * 32 + q2 * 8;
    floatx4 acc0 = {0.f, 0.f, 0.f, 0.f};
    for (int kt = 0; kt < 32; kt += 2) {
        {
            const short8 ah = *(const short8*)(sHi + kt * 512 + a_even);
            const short8 al = *(const short8*)(sLo + kt * 512 + a_even);
            const short8 bh = *(const short8*)(bph + kt * 4096);
            const short8 bl = *(const short8*)(bpl + kt * 4096);
            acc0 = __builtin_amdgcn_mfma_f32_16x16x32_bf16(ah, bh, acc0, 0, 0, 0);
            acc0 = __builtin_amdgcn_mfma_f32_16x16x32_bf16(ah, bl, acc0, 0, 0, 0);
            acc0 = __builtin_amdgcn_mfma_f32_16x16x32_bf16(al, bh, acc0, 0, 0, 0);
        }
        {
            const int kto = kt + 1;
            const short8 ah = *(const short8*)(sHi + kto * 512 + a_odd);
            const short8 al = *(const short8*)(sLo + kto * 512 + a_odd);
            const short8 bh = *(const short8*)(bph + kto * 4096);
            const short8 bl = *(const short8*)(bpl + kto * 4096);
            acc0 = __builtin_amdgcn_mfma_f32_16x16x32_bf16(ah, bh, acc0, 0, 0, 0);
            acc0 = __builtin_amdgcn_mfma_f32_16x16x32_bf16(ah, bl, acc0, 0, 0, 0);
            acc0 = __builtin_amdgcn_mfma_f32_16x16x32_bf16(al, bh, acc0, 0, 0, 0);
        }
    }
    const float b0 = bias[n0];
#pragma unroll
    for (int r = 0; r < 4; r++) {
        const int node = blockIdx.x * NB + q2 * 4 + r;  // C/D: row=(lane>>4)*4+reg, col=lane&15
        float v0 = acc0[r] + b0;
        if (RELU) v0 = fmaxf(v0, 0.f);
        hout[(size_t)node * DIM + n0] = v0;
    }
}

// gate[n] = dot(h3[n,:], gate_w) + gate_b  (one wave per node)
__global__ void k_gate(const float* __restrict__ h3, const float* __restrict__ gw,
                       const float* __restrict__ gb, float* __restrict__ gate, int N) {
    const int n = blockIdx.x * 4 + (threadIdx.x >> 6);
    const int lane = threadIdx.x & 63;
    if (n >= N) return;
    const float2 v = *(const float2*)(h3 + (size_t)n * DIM + lane * 2);
    const float2 g = *(const float2*)(gw + lane * 2);
    float p = v.x * g.x + v.y * g.y;
#pragma unroll
    for (int off = 32; off > 0; off >>= 1) p += __shfl_down(p, off, 64);
    if (lane == 0) gate[n] = p + gb[0];
}

// One block (256 threads) per graph: segment softmax + weighted readout + MLP head + sigmoid.
__global__ __launch_bounds__(256) void k_pool(
    const float* __restrict__ h3, const float* __restrict__ gate, const int* __restrict__ n2g,
    const float* __restrict__ fc1w, const float* __restrict__ fc1b,
    const float* __restrict__ fc2w, const float* __restrict__ fc2b,
    const float* __restrict__ fc3w, const float* __restrict__ fc3b,
    float* __restrict__ out, int N) {
    const int g = blockIdx.x;
    const int tid = threadIdx.x;
    __shared__ float sred[256];
    __shared__ float sr[128];
    __shared__ float sz1[100];
    __shared__ float sz2[64];
    __shared__ float sm, ssum;

    const int s = lower_bound_i(n2g, N, g);
    const int e = lower_bound_i(n2g, N, g + 1);

    float m = -3.4e38f;
    for (int n = s + tid; n < e; n += 256) m = fmaxf(m, gate[n]);
    sred[tid] = m;
    __syncthreads();
    for (int off = 128; off > 0; off >>= 1) {
        if (tid < off) sred[tid] = fmaxf(sred[tid], sred[tid + off]);
        __syncthreads();
    }
    if (tid == 0) sm = sred[0];
    __syncthreads();
    const float mm = sm;

    float sum = 0.f;
    for (int n = s + tid; n < e; n += 256) sum += expf(gate[n] - mm);
    sred[tid] = sum;
    __syncthreads();
    for (int off = 128; off > 0; off >>= 1) {
        if (tid < off) sred[tid] += sred[tid + off];
        __syncthreads();
    }
    if (tid == 0) ssum = sred[0];
    __syncthreads();
    const float inv = (e > s) ? 1.0f / ssum : 0.f;

    // weighted readout: col = tid&127, node stream split across two halves
    const int col = tid & 127;
    const int half = tid >> 7;
    float acc = 0.f;
    int n = s + half;
    for (; n + 2 < e; n += 4) {  // 2 per half per iteration
        const float w0 = expf(gate[n] - mm);
        const float w1 = expf(gate[n + 2] - mm);
        const float a0 = h3[(size_t)n * DIM + col];
        const float a1 = h3[(size_t)(n + 2) * DIM + col];
        acc = fmaf(w0, a0, acc);
        acc = fmaf(w1, a1, acc);
    }
    for (; n < e; n += 2) {
        const float wgt = expf(gate[n] - mm);
        acc = fmaf(wgt, h3[(size_t)n * DIM + col], acc);
    }
    sred[tid] = acc;
    __syncthreads();
    if (tid < 128) sr[tid] = (sred[tid] + sred[tid + 128]) * inv;
    __syncthreads();

    if (tid < 100) {
        float t = fc1b[tid];
        for (int i = 0; i < 128; i++) t = fmaf(sr[i], fc1w[i * 100 + tid], t);
        sz1[tid] = fmaxf(t, 0.f);
    }
    __syncthreads();
    if (tid < 64) {
        float t = fc2b[tid];
        for (int i = 0; i < 100; i++) t = fmaf(sz1[i], fc2w[i * 64 + tid], t);
        sz2[tid] = fmaxf(t, 0.f);
    }
    __syncthreads();
    if (tid < 64) {
        float p = sz2[tid] * fc3w[tid];
#pragma unroll
        for (int off = 32; off > 0; off >>= 1) p += __shfl_down(p, off, 64);
        if (tid == 0) {
            const float z = p + fc3b[0];
            out[g] = 1.0f / (1.0f + expf(-z));
        }
    }
}

extern "C" void kernel_launch(void* const* d_in, const int* in_sizes, int n_in,
                              void* d_out, int out_size, void* d_ws, size_t ws_size,
                              hipStream_t stream) {
    (void)in_sizes; (void)n_in; (void)out_size; (void)ws_size;
    const float* features = (const float*)d_in[0];
    const int*   src      = (const int*)d_in[1];
    const int*   dst      = (const int*)d_in[2];
    const int*   etype    = (const int*)d_in[3];
    const int*   n2g      = (const int*)d_in[4];
    const float* bases1   = (const float*)d_in[5];
    const float* comp1    = (const float*)d_in[6];
    const float* bias1    = (const float*)d_in[7];
    const float* bases2   = (const float*)d_in[8];
    const float* comp2    = (const float*)d_in[9];
    const float* bias2    = (const float*)d_in[10];
    const float* bases3   = (const float*)d_in[11];
    const float* comp3    = (const float*)d_in[12];
    const float* bias3    = (const float*)d_in[13];
    const float* gate_w   = (const float*)d_in[14];
    const float* gate_b   = (const float*)d_in[15];
    const float* fc1w     = (const float*)d_in[16];
    const float* fc1b     = (const float*)d_in[17];
    const float* fc2w     = (const float*)d_in[18];
    const float* fc2b     = (const float*)d_in[19];
    const float* fc3w     = (const float*)d_in[20];
    const float* fc3b     = (const float*)d_in[21];
    float* out = (float*)d_out;

    char* w = (char*)d_ws;
    auto alloc = [&](size_t bytes) -> char* {
        char* p = w;
        w += (bytes + 255) & ~(size_t)255;
        return p;
    };
    int*    offsets = (int*)alloc((N_NODES + 1) * sizeof(int));
    int*    cursor  = (int*)alloc((size_t)NSEG * SEG * sizeof(int));  // counts (padded), then fill cursor
    int*    edges   = (int*)alloc(N_EDGES * sizeof(int));
    int*    segscan = (int*)alloc((size_t)NSEG * SEG * sizeof(int));
    int*    segtot  = (int*)alloc(64 * sizeof(int));
    int*    segbase = (int*)alloc(64 * sizeof(int));
    float*  hA      = (float*)alloc((size_t)N_NODES * DIM * sizeof(float));
    float*  hB      = (float*)alloc((size_t)N_NODES * DIM * sizeof(float));
    float*  gate    = (float*)alloc(N_NODES * sizeof(float));
    ushort* Bhi1    = (ushort*)alloc((size_t)KDIM * DIM * sizeof(ushort));
    ushort* Blo1    = (ushort*)alloc((size_t)KDIM * DIM * sizeof(ushort));
    ushort* Bhi2    = (ushort*)alloc((size_t)KDIM * DIM * sizeof(ushort));
    ushort* Blo2    = (ushort*)alloc((size_t)KDIM * DIM * sizeof(ushort));
    ushort* Bhi3    = (ushort*)alloc((size_t)KDIM * DIM * sizeof(ushort));
    ushort* Blo3    = (ushort*)alloc((size_t)KDIM * DIM * sizeof(ushort));

    // weight packing (bf16 hi/lo, MFMA fragment order)
    k_packB<<<(KDIM * DIM) / 256, 256, 0, stream>>>(bases1, Bhi1, Blo1);
    k_packB<<<(KDIM * DIM) / 256, 256, 0, stream>>>(bases2, Bhi2, Blo2);
    k_packB<<<(KDIM * DIM) / 256, 256, 0, stream>>>(bases3, Bhi3, Blo3);

    // CSR by dst (rebuilt every call)
    hipMemsetAsync(cursor, 0, (size_t)NSEG * SEG * sizeof(int), stream);
    k_count<<<(N_EDGES + 255) / 256, 256, 0, stream>>>(dst, cursor, N_EDGES);
    k_scan_seg<<<NSEG, 256, 0, stream>>>(cursor, segscan, segtot);
    k_scan_tot<<<1, 64, 0, stream>>>(segtot, segbase);
    k_scan_fin<<<(N_NODES + 256) / 256, 256, 0, stream>>>(segscan, segbase, offsets, cursor);
    k_fill<<<(N_EDGES + 255) / 256, 256, 0, stream>>>(src, dst, etype, cursor, edges, N_EDGES);

    // 3 RGCN layers (aggregate-first + fused MFMA GEMM)
    k_layer<true><<<N_NODES / NB, 512, 0, stream>>>(features, hA, edges, offsets, comp1, Bhi1, Blo1, bias1);
    k_layer<true><<<N_NODES / NB, 512, 0, stream>>>(hA, hB, edges, offsets, comp2, Bhi2, Blo2, bias2);
    k_layer<false><<<N_NODES / NB, 512, 0, stream>>>(hB, hA, edges, offsets, comp3, Bhi3, Blo3, bias3);

    // attention gate + pooling + MLP head
    k_gate<<<N_NODES / 4, 256, 0, stream>>>(hA, gate_w, gate_b, gate, N_NODES);
    k_pool<<<N_GRAPHS, 256, 0, stream>>>(hA, gate, n2g, fc1w, fc1b, fc2w, fc2b, fc3w, fc3b, out, N_NODES);
}